// Round 13
// baseline (853.797 us; speedup 1.0000x reference)
//
#include <hip/hip_runtime.h>
#include <hip/hip_bf16.h>
#include <math.h>

typedef __hip_bfloat16 bf16;
typedef __hip_bfloat162 bf16x2;
using s8 = __attribute__((ext_vector_type(8))) short;
using h4 = __attribute__((ext_vector_type(4))) short;
using f4 = __attribute__((ext_vector_type(4))) float;

#define DEV __device__ __forceinline__
DEV float bf2f(bf16 h){ return __bfloat162float(h); }
DEV bf16  f2bf(float f){ return __float2bfloat16(f); }
DEV float silu_f(float x){ return x / (1.0f + __expf(-x)); }
// tanh-form gelu: x * sigmoid(1.59577*(x + 0.044715 x^3)); max |diff| vs erf-gelu ~3e-3
DEV float gelu_f(float x){
  float z = 1.5957691216f * x * (1.0f + 0.044715f * x * x);
  return x / (1.0f + __expf(-z));
}

// ---------------- batched weight transpose: fp32 [K,N] -> bf16 [N,K], 11 matrices ----------------
struct TDesc { const float* src; bf16* dst; int K; int N; int tiles; };
struct TPack { TDesc d[11]; };
__global__ __launch_bounds__(256) void transpose_all(TPack p){
  int tile = blockIdx.x;
  int i = 0, base = 0;
  while (i < 10 && tile >= base + p.d[i].tiles){ base += p.d[i].tiles; ++i; }
  int local = tile - base;
  const float* in = p.d[i].src;
  bf16* out = p.d[i].dst;
  int K = p.d[i].K, N = p.d[i].N;
  int ntx = N >> 5;
  int n0 = (local % ntx) * 32, k0 = (local / ntx) * 32;
  __shared__ float t[32][33];
  int tx = threadIdx.x, ty = threadIdx.y; // block (32,8)
  for (int r = ty; r < 32; r += 8) t[r][tx] = in[(size_t)(k0 + r) * N + n0 + tx];
  __syncthreads();
  for (int r = ty; r < 32; r += 8) out[(size_t)(n0 + r) * K + k0 + tx] = f2bf(t[tx][r]);
}

// ---------------- bias concat: sab=[qb|kb|vb], cab=[ckb|cvb] ----------------
__global__ __launch_bounds__(256) void concat_bias(const float* __restrict__ qb, const float* __restrict__ kb,
                                                   const float* __restrict__ vb, const float* __restrict__ ckb,
                                                   const float* __restrict__ cvb,
                                                   float* __restrict__ sab, float* __restrict__ cab){
  int t = blockIdx.x * 256 + threadIdx.x;
  if (t < 512){ sab[t] = qb[t]; cab[t] = ckb[t]; cab[512 + t] = cvb[t]; }
  else if (t < 1024){ sab[t] = kb[t - 512]; }
  else if (t < 1536){ sab[t] = vb[t - 1024]; }
}

// ---------------- LayerNorm: fp32 [rows,512] -> bf16; one row per WAVE (64 lanes x 32B) ----------------
__global__ __launch_bounds__(256) void ln_kernel(const float* __restrict__ in, bf16* __restrict__ out,
                                                 const float* __restrict__ g, const float* __restrict__ b){
  int row = blockIdx.x * 4 + (threadIdx.x >> 6);
  int lane = threadIdx.x & 63;
  const float* r = in + (size_t)row * 512 + lane * 8;
  float4 v0 = *(const float4*)r;
  float4 v1 = *(const float4*)(r + 4);
  float f[8] = {v0.x, v0.y, v0.z, v0.w, v1.x, v1.y, v1.z, v1.w};
  float s = 0.0f, s2 = 0.0f;
  #pragma unroll
  for (int j = 0; j < 8; ++j){ s += f[j]; s2 += f[j] * f[j]; }
  #pragma unroll
  for (int o = 1; o < 64; o <<= 1){ s += __shfl_xor(s, o); s2 += __shfl_xor(s2, o); }
  float mu = s * (1.0f / 512.0f);
  float var = fmaxf(s2 * (1.0f / 512.0f) - mu * mu, 0.0f);
  float rstd = rsqrtf(var + 1e-5f);
  int c = lane * 8;
  s8 o;
  #pragma unroll
  for (int j = 0; j < 8; ++j)
    ((bf16*)&o)[j] = f2bf((f[j] - mu) * rstd * g[c + j] + b[c + j]);
  *(s8*)&out[(size_t)row * 512 + c] = o;
}

// ---------- Stylization LN: bf16 y [rows,512], e fp32 [B,1024] -> bf16 silu(adaLN); row per wave ----------
__global__ __launch_bounds__(256) void styl_ln_kernel(const bf16* __restrict__ in, const float* __restrict__ e,
                                                      const float* __restrict__ g, const float* __restrict__ b,
                                                      bf16* __restrict__ out, int T){
  int row = blockIdx.x * 4 + (threadIdx.x >> 6);
  int lane = threadIdx.x & 63;
  int bidx = row / T;
  int c = lane * 8;
  s8 hv = *(const s8*)&in[(size_t)row * 512 + c];
  float f[8];
  float s = 0.0f, s2 = 0.0f;
  #pragma unroll
  for (int j = 0; j < 8; ++j){
    f[j] = bf2f(((const bf16*)&hv)[j]);
    s += f[j]; s2 += f[j] * f[j];
  }
  #pragma unroll
  for (int o = 1; o < 64; o <<= 1){ s += __shfl_xor(s, o); s2 += __shfl_xor(s2, o); }
  float mu = s * (1.0f / 512.0f);
  float var = fmaxf(s2 * (1.0f / 512.0f) - mu * mu, 0.0f);
  float rstd = rsqrtf(var + 1e-5f);
  const float* eb = e + (size_t)bidx * 1024;
  s8 o;
  #pragma unroll
  for (int j = 0; j < 8; ++j){
    float h = (f[j] - mu) * rstd * g[c + j] + b[c + j];
    h = h * (1.0f + eb[c + j]) + eb[512 + c + j];
    ((bf16*)&o)[j] = f2bf(silu_f(h));
  }
  *(s8*)&out[(size_t)row * 512 + c] = o;
}

// ---------- fused partial: att_part[c,b,h,d,l] = sum_{t in chunk c} mask_t*exp(k[t,d]) * v[t,l] ----------
__global__ __launch_bounds__(256) void kv_outer(const bf16* __restrict__ k, const bf16* __restrict__ v,
                                                const float* __restrict__ mask,
                                                float* __restrict__ att_part, float* __restrict__ den_part,
                                                int T, int ld, int Tc){
  int bh = blockIdx.x;            // b*8+h
  int b = bh >> 3, h = bh & 7;
  int chunk = blockIdx.y;
  int t_begin = chunk * Tc;
  __shared__ float kexp[64][64];
  __shared__ bf16 vb[64][64];
  int tid = threadIdx.x;
  int lg = tid & 15, tg = tid >> 4;
  int d0 = tg * 4, l0 = lg * 4;
  const float* mrow = mask ? (mask + (size_t)b * T) : nullptr;
  float acc[4][4] = {};
  float sden[4] = {0.0f, 0.0f, 0.0f, 0.0f};
  for (int tcb = t_begin; tcb < t_begin + Tc; tcb += 64){
    __syncthreads();
    #pragma unroll
    for (int i = 0; i < 2; ++i){
      int rr = (tid >> 3) + i * 32;
      int cc = (tid & 7) * 8;
      size_t goff = ((size_t)(b * T + tcb + rr)) * ld + h * 64 + cc;
      s8 kv8 = *(const s8*)&k[goff];
      *(s8*)&vb[rr][cc] = *(const s8*)&v[goff];
      float mk = mrow ? mrow[tcb + rr] : 1.0f;
      float4 e0, e1;
      e0.x = mk * __expf(bf2f(((const bf16*)&kv8)[0]));
      e0.y = mk * __expf(bf2f(((const bf16*)&kv8)[1]));
      e0.z = mk * __expf(bf2f(((const bf16*)&kv8)[2]));
      e0.w = mk * __expf(bf2f(((const bf16*)&kv8)[3]));
      e1.x = mk * __expf(bf2f(((const bf16*)&kv8)[4]));
      e1.y = mk * __expf(bf2f(((const bf16*)&kv8)[5]));
      e1.z = mk * __expf(bf2f(((const bf16*)&kv8)[6]));
      e1.w = mk * __expf(bf2f(((const bf16*)&kv8)[7]));
      *(float4*)&kexp[rr][cc]     = e0;
      *(float4*)&kexp[rr][cc + 4] = e1;
    }
    __syncthreads();
    for (int tt = 0; tt < 64; ++tt){
      float4 kf = *(const float4*)&kexp[tt][d0];
      float kk[4] = {kf.x, kf.y, kf.z, kf.w};
      float vv[4];
      #pragma unroll
      for (int j = 0; j < 4; ++j) vv[j] = bf2f(vb[tt][l0 + j]);
      #pragma unroll
      for (int a = 0; a < 4; ++a){
        sden[a] += kk[a];
        #pragma unroll
        for (int c2 = 0; c2 < 4; ++c2) acc[a][c2] += kk[a] * vv[c2];
      }
    }
  }
  size_t base = ((size_t)(chunk * 256 + bh)) * 4096;
  #pragma unroll
  for (int a = 0; a < 4; ++a)
    #pragma unroll
    for (int c2 = 0; c2 < 4; ++c2) att_part[base + (size_t)(d0 + a) * 64 + l0 + c2] = acc[a][c2];
  if (lg == 0){
    size_t dbase = ((size_t)(chunk * 256 + bh)) * 64;
    #pragma unroll
    for (int a = 0; a < 4; ++a) den_part[dbase + d0 + a] = sden[a];
  }
}

// ---------- att[b,h,d,l] = (sum_c att_part) / (sum_c den_part) ----------
__global__ __launch_bounds__(256) void kv_reduce(const float* __restrict__ att_part,
                                                 const float* __restrict__ den_part,
                                                 float* __restrict__ att, int nchunk){
  int bh = blockIdx.x, tid = threadIdx.x;
  __shared__ float dinv[64];
  if (tid < 64){
    float d = 0.0f;
    for (int c = 0; c < nchunk; ++c) d += den_part[((size_t)(c * 256 + bh)) * 64 + tid];
    dinv[tid] = 1.0f / d;
  }
  __syncthreads();
  #pragma unroll
  for (int i = 0; i < 16; ++i){
    int e = i * 256 + tid;
    float s = 0.0f;
    for (int c = 0; c < nchunk; ++c) s += att_part[((size_t)(c * 256 + bh)) * 4096 + e];
    att[(size_t)bh * 4096 + e] = s * dinv[e >> 6];
  }
}

// ---------- y[b,t,h,l] = sum_d softmax_feat(q)[b,t,h,d] * att[b,h,d,l] ----------
__global__ __launch_bounds__(256) void q_att(const bf16* __restrict__ q, const float* __restrict__ att,
                                             bf16* __restrict__ y, int T, int ldq){
  int ntc = T >> 6;
  int idx = blockIdx.x;
  int tcb = idx % ntc; int h = (idx / ntc) & 7; int b = idx / (ntc * 8);
  __shared__ float ab[64][64];
  __shared__ bf16 qb[64][64];   // XOR-swizzled columns: c' = c ^ ((row&7)<<3)
  int tid = threadIdx.x;
  #pragma unroll
  for (int i = 0; i < 4; ++i){
    int e = i * 1024 + tid * 4;
    *(float4*)&ab[e >> 6][e & 63] = *(const float4*)&att[((size_t)(b * 8 + h)) * 4096 + e];
  }
  #pragma unroll
  for (int i = 0; i < 2; ++i){
    int rr = (tid >> 3) + i * 32;
    int cc = (tid & 7) * 8;
    s8 v = *(const s8*)&q[((size_t)(b * T + tcb * 64 + rr)) * ldq + h * 64 + cc];
    float f[8];
    #pragma unroll
    for (int j = 0; j < 8; ++j) f[j] = bf2f(((const bf16*)&v)[j]);
    float m = f[0];
    #pragma unroll
    for (int j = 1; j < 8; ++j) m = fmaxf(m, f[j]);
    m = fmaxf(m, __shfl_xor(m, 1));
    m = fmaxf(m, __shfl_xor(m, 2));
    m = fmaxf(m, __shfl_xor(m, 4));
    float s = 0.0f;
    #pragma unroll
    for (int j = 0; j < 8; ++j){ f[j] = __expf(f[j] - m); s += f[j]; }
    s += __shfl_xor(s, 1);
    s += __shfl_xor(s, 2);
    s += __shfl_xor(s, 4);
    float inv = 1.0f / s;
    s8 o;
    #pragma unroll
    for (int j = 0; j < 8; ++j) ((bf16*)&o)[j] = f2bf(f[j] * inv);
    *(s8*)&qb[rr][cc ^ ((rr & 7) << 3)] = o;
  }
  __syncthreads();
  int lg = tid & 15, tg = tid >> 4;
  int t0 = tg * 4, l0 = lg * 4;
  float acc[4][4] = {};
  for (int dd = 0; dd < 64; ++dd){
    float qv[4], av[4];
    #pragma unroll
    for (int j = 0; j < 4; ++j){
      int row = t0 + j;
      qv[j] = bf2f(qb[row][dd ^ ((row & 7) << 3)]);
      av[j] = ab[dd][l0 + j];
    }
    #pragma unroll
    for (int a = 0; a < 4; ++a)
      #pragma unroll
      for (int c2 = 0; c2 < 4; ++c2) acc[a][c2] += qv[a] * av[c2];
  }
  #pragma unroll
  for (int a = 0; a < 4; ++a)
    #pragma unroll
    for (int c2 = 0; c2 < 4; ++c2)
      y[((size_t)(b * T + tcb * 64 + t0 + a)) * 512 + h * 64 + l0 + c2] = f2bf(acc[a][c2]);
}

// ---------- e_all[which][b][col] = silu(emb[b]) @ W_which + b_which ; [3,32,1024] fp32 ----------
__global__ __launch_bounds__(256) void emb_gemm(const float* __restrict__ emb,
    const float* __restrict__ w0, const float* __restrict__ b0,
    const float* __restrict__ w1, const float* __restrict__ b1,
    const float* __restrict__ w2, const float* __restrict__ b2,
    float* __restrict__ e_all){
  int col = blockIdx.x * 256 + threadIdx.x;
  int b = blockIdx.y, which = blockIdx.z;
  const float* W  = (which == 0) ? w0 : (which == 1 ? w1 : w2);
  const float* bb = (which == 0) ? b0 : (which == 1 ? b1 : b2);
  __shared__ float s[512];
  for (int i = threadIdx.x; i < 512; i += 256){ float v = emb[b * 512 + i]; s[i] = silu_f(v); }
  __syncthreads();
  float acc = bb[col];
  for (int kk = 0; kk < 512; ++kk) acc += s[kk] * W[(size_t)kk * 1024 + col];
  e_all[((size_t)which * 32 + b) * 1024 + col] = acc;
}

// ---------------- bf16 MFMA GEMM, counted-vmcnt depth-2 pipeline + hybrid epilogue ----------------
// 3 LDS buffers (48KB -> 3 blocks/CU), prefetch distance 2, ONE {vmcnt(4); s_barrier} per K-step
// (vmcnt(0) only on the peeled last step). Race-freedom:
//   RAW: per-wave vmcnt(4) drains its stage(t) loads; barrier => all waves' loads landed pre-ds_read.
//   WAR: stage(t+2) hits buf[(t+2)%3], last read at step t-1; every wave's step-(t-1) ds_reads
//        complete (lgkm) before it reaches the top-of-t barrier; stage issued only after the barrier.
// NOTE: out/out2 must never alias A (cross-block WAR race — round-10 lesson).
// EPI: 0 = bf16 store (+bias); 2 = bf16 store gelu(+bias);
//      3 = fp32 out += (+bias);  4 = fp32 out = extra + (+bias);
//      5 = fp32 out += (+bias), AND bf16 copy of new value to out2;
//      6 = bf16 store (+bias), times extra[row] for cols >= 1024 (fused SA QKV)
#define WBAR(N) asm volatile("s_waitcnt vmcnt(" #N ")\n\ts_barrier" ::: "memory")

template<int EPI>
__global__ __launch_bounds__(256, 2) void gemm_bt(
    const bf16* __restrict__ A, const bf16* __restrict__ BT,
    const float* __restrict__ bias, void* __restrict__ out,
    const float* __restrict__ extra, void* __restrict__ out2, int M, int N, int K){
  constexpr bool SW = (EPI == 3 || EPI == 4 || EPI == 5);
  __shared__ __align__(16) bf16 As[3][128 * 32];
  __shared__ __align__(16) bf16 Bs[3][128 * 32];
  int tid = threadIdx.x;
  int w = tid >> 6, lane = tid & 63;
  int wr = w >> 1, wc = w & 1;
  // ---- XCD-aware bijective block swizzle (T1, m204 form) ----
  int nwg = gridDim.x * gridDim.y;
  int lin = blockIdx.y * gridDim.x + blockIdx.x;
  int xcd = lin & 7, sidx = lin >> 3;
  int q8 = nwg >> 3, r8 = nwg & 7;
  int wg = (xcd < r8 ? xcd * (q8 + 1) : r8 * (q8 + 1) + (xcd - r8) * q8) + sidx;
  int bn = wg % gridDim.x, bm = wg / gridDim.x;

  const bf16* Ab = A  + (size_t)bm * 128 * K;
  const bf16* Bb = BT + (size_t)bn * 128 * K;

  int srow = tid >> 2;            // tid*8 / 32
  int scol = (tid & 3) * 8;

  auto stage = [&](int buf, int k0){
    #pragma unroll
    for (int i = 0; i < 2; ++i){
      const bf16* ga = Ab + (size_t)(srow + i * 64) * K + k0 + scol;
      const bf16* gb = Bb + (size_t)(srow + i * 64) * K + k0 + scol;
      bf16* la = &As[buf][i * 2048 + w * 512];
      bf16* lb = &Bs[buf][i * 2048 + w * 512];
      __builtin_amdgcn_global_load_lds((const __attribute__((address_space(1))) void*)ga,
                                       (__attribute__((address_space(3))) void*)la, 16, 0, 0);
      __builtin_amdgcn_global_load_lds((const __attribute__((address_space(1))) void*)gb,
                                       (__attribute__((address_space(3))) void*)lb, 16, 0, 0);
    }
  };

  f4 acc[4][4];
  #pragma unroll
  for (int m = 0; m < 4; ++m)
    #pragma unroll
    for (int n = 0; n < 4; ++n)
      #pragma unroll
      for (int j = 0; j < 4; ++j) acc[m][n][j] = 0.0f;

  int nt = K >> 5;
  int arow = lane & 15;
  int koff = (lane >> 4) * 8;

  auto compute = [&](int buf){
    s8 af[4], bfv[4];
    #pragma unroll
    for (int m = 0; m < 4; ++m)
      af[m] = *(const s8*)&As[buf][(wr * 64 + m * 16 + arow) * 32 + koff];
    #pragma unroll
    for (int n = 0; n < 4; ++n)
      bfv[n] = *(const s8*)&Bs[buf][(wc * 64 + n * 16 + arow) * 32 + koff];
    #pragma unroll
    for (int m = 0; m < 4; ++m)
      #pragma unroll
      for (int n = 0; n < 4; ++n){
        if constexpr (SW)
          acc[m][n] = __builtin_amdgcn_mfma_f32_16x16x32_bf16(bfv[n], af[m], acc[m][n], 0, 0, 0);
        else
          acc[m][n] = __builtin_amdgcn_mfma_f32_16x16x32_bf16(af[m], bfv[n], acc[m][n], 0, 0, 0);
      }
  };

  // prologue: 2 stages in flight (8 loads)
  stage(0, 0);
  stage(1, 32);
  int cur = 0;
  for (int t = 0; t < nt - 1; ++t){
    WBAR(4);                       // stage(t) landed for ALL waves; also orders reads(t-1) vs stage(t+2)
    if (t + 2 < nt){
      int nb = cur + 2; if (nb >= 3) nb -= 3;
      stage(nb, (t + 2) * 32);
    }
    compute(cur);
    ++cur; if (cur == 3) cur = 0;
  }
  WBAR(0);                         // drain stage(nt-1)
  compute(cur);

  if constexpr (SW){
    // swapped layout: row = rbase + m*16 (fixed/lane), col = cbase + n*16 + j (4 consecutive)
    int rbase = bm * 128 + wr * 64 + (lane & 15);
    int cbase = bn * 128 + wc * 64 + (lane >> 4) * 4;
    #pragma unroll
    for (int m = 0; m < 4; ++m){
      int row = rbase + m * 16;
      #pragma unroll
      for (int n = 0; n < 4; ++n){
        int col = cbase + n * 16;
        float4 bv = *(const float4*)&bias[col];
        float v0 = acc[m][n][0] + bv.x;
        float v1 = acc[m][n][1] + bv.y;
        float v2 = acc[m][n][2] + bv.z;
        float v3 = acc[m][n][3] + bv.w;
        size_t oi = (size_t)row * N + col;
        if (EPI == 3){
          float4* po = (float4*)&((float*)out)[oi];
          float4 c = *po;
          c.x += v0; c.y += v1; c.z += v2; c.w += v3;
          *po = c;
        } else if (EPI == 4){
          float4 e = *(const float4*)&extra[oi];
          float4 r = {e.x + v0, e.y + v1, e.z + v2, e.w + v3};
          *(float4*)&((float*)out)[oi] = r;
        } else {
          float4* po = (float4*)&((float*)out)[oi];
          float4 c = *po;
          c.x += v0; c.y += v1; c.z += v2; c.w += v3;
          *po = c;
          h4 o;
          ((bf16*)&o)[0] = f2bf(c.x); ((bf16*)&o)[1] = f2bf(c.y);
          ((bf16*)&o)[2] = f2bf(c.z); ((bf16*)&o)[3] = f2bf(c.w);
          *(h4*)&((bf16*)out2)[oi] = o;
        }
      }
    }
  } else {
    // original layout: row = r0 + m*16 + j, col = c0 + n*16 (lane-contiguous cols)
    int r0 = bm * 128 + wr * 64 + (lane >> 4) * 4;
    int c0 = bn * 128 + wc * 64 + (lane & 15);
    #pragma unroll
    for (int m = 0; m < 4; ++m){
      #pragma unroll
      for (int n = 0; n < 4; ++n){
        int col = c0 + n * 16;
        float bv = bias[col];
        #pragma unroll
        for (int j = 0; j < 4; ++j){
          int row = r0 + m * 16 + j;
          float v = acc[m][n][j] + bv;
          size_t oi = (size_t)row * N + col;
          if (EPI == 0){
            ((bf16*)out)[oi] = f2bf(v);
          } else if (EPI == 2){
            ((bf16*)out)[oi] = f2bf(gelu_f(v));
          } else { // EPI 6: fused QKV, mask V block (cols >= 1024)
            float sc = (col >= 1024) ? extra[row] : 1.0f;
            ((bf16*)out)[oi] = f2bf(v * sc);
          }
        }
      }
    }
  }
}

// =====================================================================================
extern "C" void kernel_launch(void* const* d_in, const int* in_sizes, int n_in,
                              void* d_out, int out_size, void* d_ws, size_t ws_size,
                              hipStream_t stream){
  const float* x    = (const float*)d_in[0];
  const float* xf   = (const float*)d_in[1];
  const float* emb  = (const float*)d_in[2];
  const float* mask = (const float*)d_in[3];
  const float* P[40];
  for (int j = 0; j < 40; ++j) P[j] = (const float*)d_in[4 + j];
  enum { SA_NG, SA_NB, SA_QW, SA_QB, SA_KW, SA_KB, SA_VW, SA_VB, SA_EW, SA_EB, SA_PG, SA_PB, SA_OW, SA_OB,
         CA_NG, CA_NB, CA_TG, CA_TB, CA_QW, CA_QB, CA_KW, CA_KB, CA_VW, CA_VB, CA_EW, CA_EB, CA_PG, CA_PB, CA_OW, CA_OB,
         F_W1, F_B1, F_W2, F_B2, F_EW, F_EB, F_PG, F_PB, F_OW, F_OB };

  char* wp = (char*)d_ws;
  auto alloc = [&](size_t bytes){ void* p = (void*)wp; wp += (bytes + 255) & ~(size_t)255; return p; };

  const size_t SQ = (size_t)512 * 512 * 2;       // 512x512 bf16
  bf16* WT_saqkv = (bf16*)alloc(3 * SQ);          // [1536,512]
  bf16* WT_saout = (bf16*)alloc(SQ);
  bf16* WT_caq   = (bf16*)alloc(SQ);
  bf16* WT_cakv  = (bf16*)alloc(2 * SQ);          // [1024,512]
  bf16* WT_caout = (bf16*)alloc(SQ);
  bf16* WT_f1    = (bf16*)alloc((size_t)2048 * 512 * 2);
  bf16* WT_f2    = (bf16*)alloc((size_t)512 * 2048 * 2);
  bf16* WT_fout  = (bf16*)alloc(SQ);
  float* cat_sab = (float*)alloc(1536 * 4);
  float* cat_cab = (float*)alloc(1024 * 4);
  float* e_all   = (float*)alloc((size_t)3 * 32 * 1024 * 4);

  const size_t BTD2 = (size_t)32768 * 512 * 2;    // 32 MB (bf16 [B*T, D])
  bf16* bxn  = (bf16*)alloc(BTD2);                // \ contiguous 128MB span:
  bf16* bqkv = (bf16*)alloc(3 * BTD2);            // /  reused as FFN hidden
  bf16* by   = (bf16*)alloc(BTD2);
  bf16* bs   = (bf16*)alloc(BTD2);
  bf16* btn  = (bf16*)alloc((size_t)8192 * 512 * 2);
  float* att_part = (float*)alloc((size_t)4 * 256 * 4096 * 4);   // up to 4 chunks
  float* den_part = (float*)alloc((size_t)4 * 256 * 64 * 4);
  float* batt = (float*)alloc((size_t)256 * 4096 * 4);
  bf16* bh1 = bxn;                                // FFN hidden [32768,2048] overlays bxn+bqkv
  bf16* bq_ca  = bqkv;                            // CA q  [32768,512]
  bf16* bkv_ca = bqkv + BTD2 / 2;                 // CA kv [8192,1024]

  // ---- single batched transpose dispatch (11 matrices) ----
  TPack tp;
  auto set = [&](int i, const float* s, bf16* d, int K, int N){
    tp.d[i].src = s; tp.d[i].dst = d; tp.d[i].K = K; tp.d[i].N = N;
    tp.d[i].tiles = (K >> 5) * (N >> 5);
  };
  set(0,  P[SA_QW], WT_saqkv,              512, 512);
  set(1,  P[SA_KW], WT_saqkv + 512 * 512,  512, 512);
  set(2,  P[SA_VW], WT_saqkv + 1024 * 512, 512, 512);
  set(3,  P[SA_OW], WT_saout,              512, 512);
  set(4,  P[CA_QW], WT_caq,                512, 512);
  set(5,  P[CA_KW], WT_cakv,               512, 512);
  set(6,  P[CA_VW], WT_cakv + 512 * 512,   512, 512);
  set(7,  P[CA_OW], WT_caout,              512, 512);
  set(8,  P[F_OW],  WT_fout,               512, 512);
  set(9,  P[F_W1],  WT_f1,                 512, 2048);
  set(10, P[F_W2],  WT_f2,                 2048, 512);
  int total_tiles = 9 * 256 + 1024 + 1024;   // 4352
  transpose_all<<<total_tiles, dim3(32, 8), 0, stream>>>(tp);

  concat_bias<<<6, 256, 0, stream>>>(P[SA_QB], P[SA_KB], P[SA_VB], P[CA_KB], P[CA_VB], cat_sab, cat_cab);

  emb_gemm<<<dim3(4, 32, 3), 256, 0, stream>>>(emb, P[SA_EW], P[SA_EB], P[CA_EW], P[CA_EB],
                                               P[F_EW], P[F_EB], e_all);

  dim3 g512(4, 256);   // N=512, M=32768

  // ---------------- self-attention ----------------
  ln_kernel<<<8192, 256, 0, stream>>>(x, bxn, P[SA_NG], P[SA_NB]);
  gemm_bt<6><<<dim3(12, 256), 256, 0, stream>>>(bxn, WT_saqkv, cat_sab, bqkv, mask, nullptr, 32768, 1536, 512);
  kv_outer<<<dim3(256, 4), 256, 0, stream>>>(bqkv + 512, bqkv + 1024, mask, att_part, den_part, 1024, 1536, 256);
  kv_reduce<<<256, 256, 0, stream>>>(att_part, den_part, batt, 4);
  q_att<<<4096, 256, 0, stream>>>(bqkv, batt, by, 1024, 1536);
  styl_ln_kernel<<<8192, 256, 0, stream>>>(by, e_all, P[SA_PG], P[SA_PB], bs, 1024);
  gemm_bt<4><<<g512, 256, 0, stream>>>(bs, WT_saout, P[SA_OB], d_out, x, nullptr, 32768, 512, 512);

  // ---------------- cross-attention ----------------
  ln_kernel<<<8192, 256, 0, stream>>>((const float*)d_out, bxn, P[CA_NG], P[CA_NB]);
  ln_kernel<<<2048, 256, 0, stream>>>(xf, btn, P[CA_TG], P[CA_TB]);
  gemm_bt<0><<<g512, 256, 0, stream>>>(bxn, WT_caq, P[CA_QB], bq_ca, nullptr, nullptr, 32768, 512, 512);
  gemm_bt<0><<<dim3(8, 64), 256, 0, stream>>>(btn, WT_cakv, cat_cab, bkv_ca, nullptr, nullptr, 8192, 1024, 512);
  kv_outer<<<dim3(256, 2), 256, 0, stream>>>(bkv_ca, bkv_ca + 512, nullptr, att_part, den_part, 256, 1024, 128);
  kv_reduce<<<256, 256, 0, stream>>>(att_part, den_part, batt, 2);
  q_att<<<4096, 256, 0, stream>>>(bq_ca, batt, by, 1024, 512);
  styl_ln_kernel<<<8192, 256, 0, stream>>>(by, e_all + 32 * 1024, P[CA_PG], P[CA_PB], bs, 1024);
  // out2 = by (NOT bs): A and out2 must not alias (cross-block WAR race)
  gemm_bt<5><<<g512, 256, 0, stream>>>(bs, WT_caout, P[CA_OB], d_out, nullptr, by, 32768, 512, 512);

  // ---------------- FFN ----------------
  gemm_bt<2><<<dim3(16, 256), 256, 0, stream>>>(by, WT_f1, P[F_B1], bh1, nullptr, nullptr, 32768, 2048, 512);
  gemm_bt<0><<<dim3(4, 256), 256, 0, stream>>>(bh1, WT_f2, P[F_B2], bs, nullptr, nullptr, 32768, 512, 2048);
  styl_ln_kernel<<<8192, 256, 0, stream>>>(bs, e_all + 2 * 32 * 1024, P[F_PG], P[F_PB], by, 1024);
  gemm_bt<3><<<g512, 256, 0, stream>>>(by, WT_fout, P[F_OB], d_out, nullptr, nullptr, 32768, 512, 512);
}

// Round 14
// 788.608 us; speedup vs baseline: 1.0827x; 1.0827x over previous
//
#include <hip/hip_runtime.h>
#include <hip/hip_bf16.h>
#include <math.h>

typedef __hip_bfloat16 bf16;
typedef __hip_bfloat162 bf16x2;
using s8 = __attribute__((ext_vector_type(8))) short;
using h4 = __attribute__((ext_vector_type(4))) short;
using f4 = __attribute__((ext_vector_type(4))) float;

#define DEV __device__ __forceinline__
DEV float bf2f(bf16 h){ return __bfloat162float(h); }
DEV bf16  f2bf(float f){ return __float2bfloat16(f); }
DEV float silu_f(float x){ return x / (1.0f + __expf(-x)); }
// tanh-form gelu: x * sigmoid(1.59577*(x + 0.044715 x^3)); max |diff| vs erf-gelu ~3e-3
DEV float gelu_f(float x){
  float z = 1.5957691216f * x * (1.0f + 0.044715f * x * x);
  return x / (1.0f + __expf(-z));
}

// ---------------- batched weight transpose: fp32 [K,N] -> bf16 [N,K], 11 matrices ----------------
struct TDesc { const float* src; bf16* dst; int K; int N; int tiles; };
struct TPack { TDesc d[11]; };
__global__ __launch_bounds__(256) void transpose_all(TPack p){
  int tile = blockIdx.x;
  int i = 0, base = 0;
  while (i < 10 && tile >= base + p.d[i].tiles){ base += p.d[i].tiles; ++i; }
  int local = tile - base;
  const float* in = p.d[i].src;
  bf16* out = p.d[i].dst;
  int K = p.d[i].K, N = p.d[i].N;
  int ntx = N >> 5;
  int n0 = (local % ntx) * 32, k0 = (local / ntx) * 32;
  __shared__ float t[32][33];
  int tx = threadIdx.x, ty = threadIdx.y; // block (32,8)
  for (int r = ty; r < 32; r += 8) t[r][tx] = in[(size_t)(k0 + r) * N + n0 + tx];
  __syncthreads();
  for (int r = ty; r < 32; r += 8) out[(size_t)(n0 + r) * K + k0 + tx] = f2bf(t[tx][r]);
}

// ---------------- bias concat: sab=[qb|kb|vb], cab=[ckb|cvb] ----------------
__global__ __launch_bounds__(256) void concat_bias(const float* __restrict__ qb, const float* __restrict__ kb,
                                                   const float* __restrict__ vb, const float* __restrict__ ckb,
                                                   const float* __restrict__ cvb,
                                                   float* __restrict__ sab, float* __restrict__ cab){
  int t = blockIdx.x * 256 + threadIdx.x;
  if (t < 512){ sab[t] = qb[t]; cab[t] = ckb[t]; cab[512 + t] = cvb[t]; }
  else if (t < 1024){ sab[t] = kb[t - 512]; }
  else if (t < 1536){ sab[t] = vb[t - 1024]; }
}

// ---------------- LayerNorm: fp32 [rows,512] -> bf16; one row per WAVE (64 lanes x 32B) ----------------
__global__ __launch_bounds__(256) void ln_kernel(const float* __restrict__ in, bf16* __restrict__ out,
                                                 const float* __restrict__ g, const float* __restrict__ b){
  int row = blockIdx.x * 4 + (threadIdx.x >> 6);
  int lane = threadIdx.x & 63;
  const float* r = in + (size_t)row * 512 + lane * 8;
  float4 v0 = *(const float4*)r;
  float4 v1 = *(const float4*)(r + 4);
  float f[8] = {v0.x, v0.y, v0.z, v0.w, v1.x, v1.y, v1.z, v1.w};
  float s = 0.0f, s2 = 0.0f;
  #pragma unroll
  for (int j = 0; j < 8; ++j){ s += f[j]; s2 += f[j] * f[j]; }
  #pragma unroll
  for (int o = 1; o < 64; o <<= 1){ s += __shfl_xor(s, o); s2 += __shfl_xor(s2, o); }
  float mu = s * (1.0f / 512.0f);
  float var = fmaxf(s2 * (1.0f / 512.0f) - mu * mu, 0.0f);
  float rstd = rsqrtf(var + 1e-5f);
  int c = lane * 8;
  s8 o;
  #pragma unroll
  for (int j = 0; j < 8; ++j)
    ((bf16*)&o)[j] = f2bf((f[j] - mu) * rstd * g[c + j] + b[c + j]);
  *(s8*)&out[(size_t)row * 512 + c] = o;
}

// ---------- Stylization LN: bf16 y [rows,512], e fp32 [B,1024] -> bf16 silu(adaLN); row per wave ----------
__global__ __launch_bounds__(256) void styl_ln_kernel(const bf16* __restrict__ in, const float* __restrict__ e,
                                                      const float* __restrict__ g, const float* __restrict__ b,
                                                      bf16* __restrict__ out, int T){
  int row = blockIdx.x * 4 + (threadIdx.x >> 6);
  int lane = threadIdx.x & 63;
  int bidx = row / T;
  int c = lane * 8;
  s8 hv = *(const s8*)&in[(size_t)row * 512 + c];
  float f[8];
  float s = 0.0f, s2 = 0.0f;
  #pragma unroll
  for (int j = 0; j < 8; ++j){
    f[j] = bf2f(((const bf16*)&hv)[j]);
    s += f[j]; s2 += f[j] * f[j];
  }
  #pragma unroll
  for (int o = 1; o < 64; o <<= 1){ s += __shfl_xor(s, o); s2 += __shfl_xor(s2, o); }
  float mu = s * (1.0f / 512.0f);
  float var = fmaxf(s2 * (1.0f / 512.0f) - mu * mu, 0.0f);
  float rstd = rsqrtf(var + 1e-5f);
  const float* eb = e + (size_t)bidx * 1024;
  s8 o;
  #pragma unroll
  for (int j = 0; j < 8; ++j){
    float h = (f[j] - mu) * rstd * g[c + j] + b[c + j];
    h = h * (1.0f + eb[c + j]) + eb[512 + c + j];
    ((bf16*)&o)[j] = f2bf(silu_f(h));
  }
  *(s8*)&out[(size_t)row * 512 + c] = o;
}

// ---------- fused partial: att_part[c,b,h,d,l] = sum_{t in chunk c} mask_t*exp(k[t,d]) * v[t,l] ----------
__global__ __launch_bounds__(256) void kv_outer(const bf16* __restrict__ k, const bf16* __restrict__ v,
                                                const float* __restrict__ mask,
                                                float* __restrict__ att_part, float* __restrict__ den_part,
                                                int T, int ld, int Tc){
  int bh = blockIdx.x;            // b*8+h
  int b = bh >> 3, h = bh & 7;
  int chunk = blockIdx.y;
  int t_begin = chunk * Tc;
  __shared__ float kexp[64][64];
  __shared__ bf16 vb[64][64];
  int tid = threadIdx.x;
  int lg = tid & 15, tg = tid >> 4;
  int d0 = tg * 4, l0 = lg * 4;
  const float* mrow = mask ? (mask + (size_t)b * T) : nullptr;
  float acc[4][4] = {};
  float sden[4] = {0.0f, 0.0f, 0.0f, 0.0f};
  for (int tcb = t_begin; tcb < t_begin + Tc; tcb += 64){
    __syncthreads();
    #pragma unroll
    for (int i = 0; i < 2; ++i){
      int rr = (tid >> 3) + i * 32;
      int cc = (tid & 7) * 8;
      size_t goff = ((size_t)(b * T + tcb + rr)) * ld + h * 64 + cc;
      s8 kv8 = *(const s8*)&k[goff];
      *(s8*)&vb[rr][cc] = *(const s8*)&v[goff];
      float mk = mrow ? mrow[tcb + rr] : 1.0f;
      float4 e0, e1;
      e0.x = mk * __expf(bf2f(((const bf16*)&kv8)[0]));
      e0.y = mk * __expf(bf2f(((const bf16*)&kv8)[1]));
      e0.z = mk * __expf(bf2f(((const bf16*)&kv8)[2]));
      e0.w = mk * __expf(bf2f(((const bf16*)&kv8)[3]));
      e1.x = mk * __expf(bf2f(((const bf16*)&kv8)[4]));
      e1.y = mk * __expf(bf2f(((const bf16*)&kv8)[5]));
      e1.z = mk * __expf(bf2f(((const bf16*)&kv8)[6]));
      e1.w = mk * __expf(bf2f(((const bf16*)&kv8)[7]));
      *(float4*)&kexp[rr][cc]     = e0;
      *(float4*)&kexp[rr][cc + 4] = e1;
    }
    __syncthreads();
    for (int tt = 0; tt < 64; ++tt){
      float4 kf = *(const float4*)&kexp[tt][d0];
      float kk[4] = {kf.x, kf.y, kf.z, kf.w};
      float vv[4];
      #pragma unroll
      for (int j = 0; j < 4; ++j) vv[j] = bf2f(vb[tt][l0 + j]);
      #pragma unroll
      for (int a = 0; a < 4; ++a){
        sden[a] += kk[a];
        #pragma unroll
        for (int c2 = 0; c2 < 4; ++c2) acc[a][c2] += kk[a] * vv[c2];
      }
    }
  }
  size_t base = ((size_t)(chunk * 256 + bh)) * 4096;
  #pragma unroll
  for (int a = 0; a < 4; ++a)
    #pragma unroll
    for (int c2 = 0; c2 < 4; ++c2) att_part[base + (size_t)(d0 + a) * 64 + l0 + c2] = acc[a][c2];
  if (lg == 0){
    size_t dbase = ((size_t)(chunk * 256 + bh)) * 64;
    #pragma unroll
    for (int a = 0; a < 4; ++a) den_part[dbase + d0 + a] = sden[a];
  }
}

// ---------- att[b,h,d,l] = (sum_c att_part) / (sum_c den_part) ----------
__global__ __launch_bounds__(256) void kv_reduce(const float* __restrict__ att_part,
                                                 const float* __restrict__ den_part,
                                                 float* __restrict__ att, int nchunk){
  int bh = blockIdx.x, tid = threadIdx.x;
  __shared__ float dinv[64];
  if (tid < 64){
    float d = 0.0f;
    for (int c = 0; c < nchunk; ++c) d += den_part[((size_t)(c * 256 + bh)) * 64 + tid];
    dinv[tid] = 1.0f / d;
  }
  __syncthreads();
  #pragma unroll
  for (int i = 0; i < 16; ++i){
    int e = i * 256 + tid;
    float s = 0.0f;
    for (int c = 0; c < nchunk; ++c) s += att_part[((size_t)(c * 256 + bh)) * 4096 + e];
    att[(size_t)bh * 4096 + e] = s * dinv[e >> 6];
  }
}

// ---------- y[b,t,h,l] = sum_d softmax_feat(q)[b,t,h,d] * att[b,h,d,l] ----------
__global__ __launch_bounds__(256) void q_att(const bf16* __restrict__ q, const float* __restrict__ att,
                                             bf16* __restrict__ y, int T, int ldq){
  int ntc = T >> 6;
  int idx = blockIdx.x;
  int tcb = idx % ntc; int h = (idx / ntc) & 7; int b = idx / (ntc * 8);
  __shared__ float ab[64][64];
  __shared__ bf16 qb[64][64];   // XOR-swizzled columns: c' = c ^ ((row&7)<<3)
  int tid = threadIdx.x;
  #pragma unroll
  for (int i = 0; i < 4; ++i){
    int e = i * 1024 + tid * 4;
    *(float4*)&ab[e >> 6][e & 63] = *(const float4*)&att[((size_t)(b * 8 + h)) * 4096 + e];
  }
  #pragma unroll
  for (int i = 0; i < 2; ++i){
    int rr = (tid >> 3) + i * 32;
    int cc = (tid & 7) * 8;
    s8 v = *(const s8*)&q[((size_t)(b * T + tcb * 64 + rr)) * ldq + h * 64 + cc];
    float f[8];
    #pragma unroll
    for (int j = 0; j < 8; ++j) f[j] = bf2f(((const bf16*)&v)[j]);
    float m = f[0];
    #pragma unroll
    for (int j = 1; j < 8; ++j) m = fmaxf(m, f[j]);
    m = fmaxf(m, __shfl_xor(m, 1));
    m = fmaxf(m, __shfl_xor(m, 2));
    m = fmaxf(m, __shfl_xor(m, 4));
    float s = 0.0f;
    #pragma unroll
    for (int j = 0; j < 8; ++j){ f[j] = __expf(f[j] - m); s += f[j]; }
    s += __shfl_xor(s, 1);
    s += __shfl_xor(s, 2);
    s += __shfl_xor(s, 4);
    float inv = 1.0f / s;
    s8 o;
    #pragma unroll
    for (int j = 0; j < 8; ++j) ((bf16*)&o)[j] = f2bf(f[j] * inv);
    *(s8*)&qb[rr][cc ^ ((rr & 7) << 3)] = o;
  }
  __syncthreads();
  int lg = tid & 15, tg = tid >> 4;
  int t0 = tg * 4, l0 = lg * 4;
  float acc[4][4] = {};
  for (int dd = 0; dd < 64; ++dd){
    float qv[4], av[4];
    #pragma unroll
    for (int j = 0; j < 4; ++j){
      int row = t0 + j;
      qv[j] = bf2f(qb[row][dd ^ ((row & 7) << 3)]);
      av[j] = ab[dd][l0 + j];
    }
    #pragma unroll
    for (int a = 0; a < 4; ++a)
      #pragma unroll
      for (int c2 = 0; c2 < 4; ++c2) acc[a][c2] += qv[a] * av[c2];
  }
  #pragma unroll
  for (int a = 0; a < 4; ++a)
    #pragma unroll
    for (int c2 = 0; c2 < 4; ++c2)
      y[((size_t)(b * T + tcb * 64 + t0 + a)) * 512 + h * 64 + l0 + c2] = f2bf(acc[a][c2]);
}

// ---------- e_all[which][b][col] = silu(emb[b]) @ W_which + b_which ; [3,32,1024] fp32 ----------
__global__ __launch_bounds__(256) void emb_gemm(const float* __restrict__ emb,
    const float* __restrict__ w0, const float* __restrict__ b0,
    const float* __restrict__ w1, const float* __restrict__ b1,
    const float* __restrict__ w2, const float* __restrict__ b2,
    float* __restrict__ e_all){
  int col = blockIdx.x * 256 + threadIdx.x;
  int b = blockIdx.y, which = blockIdx.z;
  const float* W  = (which == 0) ? w0 : (which == 1 ? w1 : w2);
  const float* bb = (which == 0) ? b0 : (which == 1 ? b1 : b2);
  __shared__ float s[512];
  for (int i = threadIdx.x; i < 512; i += 256){ float v = emb[b * 512 + i]; s[i] = silu_f(v); }
  __syncthreads();
  float acc = bb[col];
  for (int kk = 0; kk < 512; ++kk) acc += s[kk] * W[(size_t)kk * 1024 + col];
  e_all[((size_t)which * 32 + b) * 1024 + col] = acc;
}

// ---------------- bf16 MFMA GEMM, HYBRID epilogue (round-12 proven form) ----------------
// SW = (EPI in {3,4,5}): swapped mfma operands -> lane holds 4 consecutive COLS ->
//   float4 RMW epilogue (measured win for fp32 read-modify-write, round 11).
// !SW (EPI 0,2,6): original operand order -> lane-contiguous scalar bf16 stores
//   (measured win for pure bf16 streams, round 9: FFN1/FFN2 112 vs 123 us).
// NOTE: out/out2 must never alias A (cross-block WAR race — round-10 lesson).
// EPI: 0 = bf16 store (+bias); 2 = bf16 store gelu(+bias);
//      3 = fp32 out += (+bias);  4 = fp32 out = extra + (+bias);
//      5 = fp32 out += (+bias), AND bf16 copy of new value to out2;
//      6 = bf16 store (+bias), times extra[row] for cols >= 1024 (fused SA QKV)
template<int EPI>
__global__ __launch_bounds__(256, 2) void gemm_bt(
    const bf16* __restrict__ A, const bf16* __restrict__ BT,
    const float* __restrict__ bias, void* __restrict__ out,
    const float* __restrict__ extra, void* __restrict__ out2, int M, int N, int K){
  constexpr bool SW = (EPI == 3 || EPI == 4 || EPI == 5);
  __shared__ __align__(16) bf16 As[2][128 * 32];
  __shared__ __align__(16) bf16 Bs[2][128 * 32];
  int tid = threadIdx.x;
  int w = tid >> 6, lane = tid & 63;
  int wr = w >> 1, wc = w & 1;
  // ---- XCD-aware bijective block swizzle (T1, m204 form) ----
  int nwg = gridDim.x * gridDim.y;
  int lin = blockIdx.y * gridDim.x + blockIdx.x;
  int xcd = lin & 7, sidx = lin >> 3;
  int q8 = nwg >> 3, r8 = nwg & 7;
  int wg = (xcd < r8 ? xcd * (q8 + 1) : r8 * (q8 + 1) + (xcd - r8) * q8) + sidx;
  int bn = wg % gridDim.x, bm = wg / gridDim.x;

  const bf16* Ab = A  + (size_t)bm * 128 * K;
  const bf16* Bb = BT + (size_t)bn * 128 * K;

  int srow = tid >> 2;            // tid*8 / 32
  int scol = (tid & 3) * 8;

  auto stage = [&](int buf, int k0){
    #pragma unroll
    for (int i = 0; i < 2; ++i){
      const bf16* ga = Ab + (size_t)(srow + i * 64) * K + k0 + scol;
      const bf16* gb = Bb + (size_t)(srow + i * 64) * K + k0 + scol;
      bf16* la = &As[buf][i * 2048 + w * 512];
      bf16* lb = &Bs[buf][i * 2048 + w * 512];
      __builtin_amdgcn_global_load_lds((const __attribute__((address_space(1))) void*)ga,
                                       (__attribute__((address_space(3))) void*)la, 16, 0, 0);
      __builtin_amdgcn_global_load_lds((const __attribute__((address_space(1))) void*)gb,
                                       (__attribute__((address_space(3))) void*)lb, 16, 0, 0);
    }
  };

  f4 acc[4][4];
  #pragma unroll
  for (int m = 0; m < 4; ++m)
    #pragma unroll
    for (int n = 0; n < 4; ++n)
      #pragma unroll
      for (int j = 0; j < 4; ++j) acc[m][n][j] = 0.0f;

  int nt = K >> 5;
  int arow = lane & 15;
  int koff = (lane >> 4) * 8;

  stage(0, 0);
  __syncthreads();
  int cur = 0;
  for (int t = 0; t < nt; ++t){
    if (t + 1 < nt) stage(cur ^ 1, (t + 1) * 32);
    s8 af[4], bfv[4];
    #pragma unroll
    for (int m = 0; m < 4; ++m)
      af[m] = *(const s8*)&As[cur][(wr * 64 + m * 16 + arow) * 32 + koff];
    #pragma unroll
    for (int n = 0; n < 4; ++n)
      bfv[n] = *(const s8*)&Bs[cur][(wc * 64 + n * 16 + arow) * 32 + koff];
    #pragma unroll
    for (int m = 0; m < 4; ++m)
      #pragma unroll
      for (int n = 0; n < 4; ++n){
        if constexpr (SW)
          acc[m][n] = __builtin_amdgcn_mfma_f32_16x16x32_bf16(bfv[n], af[m], acc[m][n], 0, 0, 0);
        else
          acc[m][n] = __builtin_amdgcn_mfma_f32_16x16x32_bf16(af[m], bfv[n], acc[m][n], 0, 0, 0);
      }
    __syncthreads();
    cur ^= 1;
  }

  if constexpr (SW){
    // swapped layout: row = rbase + m*16 (fixed/lane), col = cbase + n*16 + j (4 consecutive)
    int rbase = bm * 128 + wr * 64 + (lane & 15);
    int cbase = bn * 128 + wc * 64 + (lane >> 4) * 4;
    #pragma unroll
    for (int m = 0; m < 4; ++m){
      int row = rbase + m * 16;
      #pragma unroll
      for (int n = 0; n < 4; ++n){
        int col = cbase + n * 16;
        float4 bv = *(const float4*)&bias[col];
        float v0 = acc[m][n][0] + bv.x;
        float v1 = acc[m][n][1] + bv.y;
        float v2 = acc[m][n][2] + bv.z;
        float v3 = acc[m][n][3] + bv.w;
        size_t oi = (size_t)row * N + col;
        if (EPI == 3){
          float4* po = (float4*)&((float*)out)[oi];
          float4 c = *po;
          c.x += v0; c.y += v1; c.z += v2; c.w += v3;
          *po = c;
        } else if (EPI == 4){
          float4 e = *(const float4*)&extra[oi];
          float4 r = {e.x + v0, e.y + v1, e.z + v2, e.w + v3};
          *(float4*)&((float*)out)[oi] = r;
        } else {
          float4* po = (float4*)&((float*)out)[oi];
          float4 c = *po;
          c.x += v0; c.y += v1; c.z += v2; c.w += v3;
          *po = c;
          h4 o;
          ((bf16*)&o)[0] = f2bf(c.x); ((bf16*)&o)[1] = f2bf(c.y);
          ((bf16*)&o)[2] = f2bf(c.z); ((bf16*)&o)[3] = f2bf(c.w);
          *(h4*)&((bf16*)out2)[oi] = o;
        }
      }
    }
  } else {
    // original layout: row = r0 + m*16 + j, col = c0 + n*16 (lane-contiguous cols)
    int r0 = bm * 128 + wr * 64 + (lane >> 4) * 4;
    int c0 = bn * 128 + wc * 64 + (lane & 15);
    #pragma unroll
    for (int m = 0; m < 4; ++m){
      #pragma unroll
      for (int n = 0; n < 4; ++n){
        int col = c0 + n * 16;
        float bv = bias[col];
        #pragma unroll
        for (int j = 0; j < 4; ++j){
          int row = r0 + m * 16 + j;
          float v = acc[m][n][j] + bv;
          size_t oi = (size_t)row * N + col;
          if (EPI == 0){
            ((bf16*)out)[oi] = f2bf(v);
          } else if (EPI == 2){
            ((bf16*)out)[oi] = f2bf(gelu_f(v));
          } else { // EPI 6: fused QKV, mask V block (cols >= 1024)
            float sc = (col >= 1024) ? extra[row] : 1.0f;
            ((bf16*)out)[oi] = f2bf(v * sc);
          }
        }
      }
    }
  }
}

// =====================================================================================
extern "C" void kernel_launch(void* const* d_in, const int* in_sizes, int n_in,
                              void* d_out, int out_size, void* d_ws, size_t ws_size,
                              hipStream_t stream){
  const float* x    = (const float*)d_in[0];
  const float* xf   = (const float*)d_in[1];
  const float* emb  = (const float*)d_in[2];
  const float* mask = (const float*)d_in[3];
  const float* P[40];
  for (int j = 0; j < 40; ++j) P[j] = (const float*)d_in[4 + j];
  enum { SA_NG, SA_NB, SA_QW, SA_QB, SA_KW, SA_KB, SA_VW, SA_VB, SA_EW, SA_EB, SA_PG, SA_PB, SA_OW, SA_OB,
         CA_NG, CA_NB, CA_TG, CA_TB, CA_QW, CA_QB, CA_KW, CA_KB, CA_VW, CA_VB, CA_EW, CA_EB, CA_PG, CA_PB, CA_OW, CA_OB,
         F_W1, F_B1, F_W2, F_B2, F_EW, F_EB, F_PG, F_PB, F_OW, F_OB };

  char* wp = (char*)d_ws;
  auto alloc = [&](size_t bytes){ void* p = (void*)wp; wp += (bytes + 255) & ~(size_t)255; return p; };

  const size_t SQ = (size_t)512 * 512 * 2;       // 512x512 bf16
  bf16* WT_saqkv = (bf16*)alloc(3 * SQ);          // [1536,512]
  bf16* WT_saout = (bf16*)alloc(SQ);
  bf16* WT_caq   = (bf16*)alloc(SQ);
  bf16* WT_cakv  = (bf16*)alloc(2 * SQ);          // [1024,512]
  bf16* WT_caout = (bf16*)alloc(SQ);
  bf16* WT_f1    = (bf16*)alloc((size_t)2048 * 512 * 2);
  bf16* WT_f2    = (bf16*)alloc((size_t)512 * 2048 * 2);
  bf16* WT_fout  = (bf16*)alloc(SQ);
  float* cat_sab = (float*)alloc(1536 * 4);
  float* cat_cab = (float*)alloc(1024 * 4);
  float* e_all   = (float*)alloc((size_t)3 * 32 * 1024 * 4);

  const size_t BTD2 = (size_t)32768 * 512 * 2;    // 32 MB (bf16 [B*T, D])
  bf16* bxn  = (bf16*)alloc(BTD2);                // \ contiguous 128MB span:
  bf16* bqkv = (bf16*)alloc(3 * BTD2);            // /  reused as FFN hidden
  bf16* by   = (bf16*)alloc(BTD2);
  bf16* bs   = (bf16*)alloc(BTD2);
  bf16* btn  = (bf16*)alloc((size_t)8192 * 512 * 2);
  float* att_part = (float*)alloc((size_t)4 * 256 * 4096 * 4);   // up to 4 chunks
  float* den_part = (float*)alloc((size_t)4 * 256 * 64 * 4);
  float* batt = (float*)alloc((size_t)256 * 4096 * 4);
  bf16* bh1 = bxn;                                // FFN hidden [32768,2048] overlays bxn+bqkv
  bf16* bq_ca  = bqkv;                            // CA q  [32768,512]
  bf16* bkv_ca = bqkv + BTD2 / 2;                 // CA kv [8192,1024]

  // ---- single batched transpose dispatch (11 matrices) ----
  TPack tp;
  auto set = [&](int i, const float* s, bf16* d, int K, int N){
    tp.d[i].src = s; tp.d[i].dst = d; tp.d[i].K = K; tp.d[i].N = N;
    tp.d[i].tiles = (K >> 5) * (N >> 5);
  };
  set(0,  P[SA_QW], WT_saqkv,              512, 512);
  set(1,  P[SA_KW], WT_saqkv + 512 * 512,  512, 512);
  set(2,  P[SA_VW], WT_saqkv + 1024 * 512, 512, 512);
  set(3,  P[SA_OW], WT_saout,              512, 512);
  set(4,  P[CA_QW], WT_caq,                512, 512);
  set(5,  P[CA_KW], WT_cakv,               512, 512);
  set(6,  P[CA_VW], WT_cakv + 512 * 512,   512, 512);
  set(7,  P[CA_OW], WT_caout,              512, 512);
  set(8,  P[F_OW],  WT_fout,               512, 512);
  set(9,  P[F_W1],  WT_f1,                 512, 2048);
  set(10, P[F_W2],  WT_f2,                 2048, 512);
  int total_tiles = 9 * 256 + 1024 + 1024;   // 4352
  transpose_all<<<total_tiles, dim3(32, 8), 0, stream>>>(tp);

  concat_bias<<<6, 256, 0, stream>>>(P[SA_QB], P[SA_KB], P[SA_VB], P[CA_KB], P[CA_VB], cat_sab, cat_cab);

  emb_gemm<<<dim3(4, 32, 3), 256, 0, stream>>>(emb, P[SA_EW], P[SA_EB], P[CA_EW], P[CA_EB],
                                               P[F_EW], P[F_EB], e_all);

  dim3 g512(4, 256);   // N=512, M=32768

  // ---------------- self-attention ----------------
  ln_kernel<<<8192, 256, 0, stream>>>(x, bxn, P[SA_NG], P[SA_NB]);
  gemm_bt<6><<<dim3(12, 256), 256, 0, stream>>>(bxn, WT_saqkv, cat_sab, bqkv, mask, nullptr, 32768, 1536, 512);
  kv_outer<<<dim3(256, 4), 256, 0, stream>>>(bqkv + 512, bqkv + 1024, mask, att_part, den_part, 1024, 1536, 256);
  kv_reduce<<<256, 256, 0, stream>>>(att_part, den_part, batt, 4);
  q_att<<<4096, 256, 0, stream>>>(bqkv, batt, by, 1024, 1536);
  styl_ln_kernel<<<8192, 256, 0, stream>>>(by, e_all, P[SA_PG], P[SA_PB], bs, 1024);
  gemm_bt<4><<<g512, 256, 0, stream>>>(bs, WT_saout, P[SA_OB], d_out, x, nullptr, 32768, 512, 512);

  // ---------------- cross-attention ----------------
  ln_kernel<<<8192, 256, 0, stream>>>((const float*)d_out, bxn, P[CA_NG], P[CA_NB]);
  ln_kernel<<<2048, 256, 0, stream>>>(xf, btn, P[CA_TG], P[CA_TB]);
  gemm_bt<0><<<g512, 256, 0, stream>>>(bxn, WT_caq, P[CA_QB], bq_ca, nullptr, nullptr, 32768, 512, 512);
  gemm_bt<0><<<dim3(8, 64), 256, 0, stream>>>(btn, WT_cakv, cat_cab, bkv_ca, nullptr, nullptr, 8192, 1024, 512);
  kv_outer<<<dim3(256, 2), 256, 0, stream>>>(bkv_ca, bkv_ca + 512, nullptr, att_part, den_part, 256, 1024, 128);
  kv_reduce<<<256, 256, 0, stream>>>(att_part, den_part, batt, 2);
  q_att<<<4096, 256, 0, stream>>>(bq_ca, batt, by, 1024, 512);
  styl_ln_kernel<<<8192, 256, 0, stream>>>(by, e_all + 32 * 1024, P[CA_PG], P[CA_PB], bs, 1024);
  // out2 = by (NOT bs): A and out2 must not alias (cross-block WAR race)
  gemm_bt<5><<<g512, 256, 0, stream>>>(bs, WT_caout, P[CA_OB], d_out, nullptr, by, 32768, 512, 512);

  // ---------------- FFN ----------------
  gemm_bt<2><<<dim3(16, 256), 256, 0, stream>>>(by, WT_f1, P[F_B1], bh1, nullptr, nullptr, 32768, 2048, 512);
  gemm_bt<0><<<dim3(4, 256), 256, 0, stream>>>(bh1, WT_f2, P[F_B2], bs, nullptr, nullptr, 32768, 512, 2048);
  styl_ln_kernel<<<8192, 256, 0, stream>>>(bs, e_all + 2 * 32 * 1024, P[F_PG], P[F_PB], by, 1024);
  gemm_bt<3><<<g512, 256, 0, stream>>>(by, WT_fout, P[F_OB], d_out, nullptr, nullptr, 32768, 512, 512);
}

// Round 15
// 778.834 us; speedup vs baseline: 1.0963x; 1.0126x over previous
//
#include <hip/hip_runtime.h>
#include <hip/hip_bf16.h>
#include <math.h>

typedef __hip_bfloat16 bf16;
typedef __hip_bfloat162 bf16x2;
using s8 = __attribute__((ext_vector_type(8))) short;
using h4 = __attribute__((ext_vector_type(4))) short;
using f4 = __attribute__((ext_vector_type(4))) float;

#define DEV __device__ __forceinline__
DEV float bf2f(bf16 h){ return __bfloat162float(h); }
DEV bf16  f2bf(float f){ return __float2bfloat16(f); }
DEV float silu_f(float x){ return x / (1.0f + __expf(-x)); }
// tanh-form gelu: x * sigmoid(1.59577*(x + 0.044715 x^3)); max |diff| vs erf-gelu ~3e-3
DEV float gelu_f(float x){
  float z = 1.5957691216f * x * (1.0f + 0.044715f * x * x);
  return x / (1.0f + __expf(-z));
}

// ---------------- batched weight transpose: fp32 [K,N] -> bf16 [N,K], 11 matrices ----------------
struct TDesc { const float* src; bf16* dst; int K; int N; int tiles; };
struct TPack { TDesc d[11]; };
__global__ __launch_bounds__(256) void transpose_all(TPack p){
  int tile = blockIdx.x;
  int i = 0, base = 0;
  while (i < 10 && tile >= base + p.d[i].tiles){ base += p.d[i].tiles; ++i; }
  int local = tile - base;
  const float* in = p.d[i].src;
  bf16* out = p.d[i].dst;
  int K = p.d[i].K, N = p.d[i].N;
  int ntx = N >> 5;
  int n0 = (local % ntx) * 32, k0 = (local / ntx) * 32;
  __shared__ float t[32][33];
  int tx = threadIdx.x, ty = threadIdx.y; // block (32,8)
  for (int r = ty; r < 32; r += 8) t[r][tx] = in[(size_t)(k0 + r) * N + n0 + tx];
  __syncthreads();
  for (int r = ty; r < 32; r += 8) out[(size_t)(n0 + r) * K + k0 + tx] = f2bf(t[tx][r]);
}

// ---------------- bias concat: sab=[qb|kb|vb], cab=[ckb|cvb] ----------------
__global__ __launch_bounds__(256) void concat_bias(const float* __restrict__ qb, const float* __restrict__ kb,
                                                   const float* __restrict__ vb, const float* __restrict__ ckb,
                                                   const float* __restrict__ cvb,
                                                   float* __restrict__ sab, float* __restrict__ cab){
  int t = blockIdx.x * 256 + threadIdx.x;
  if (t < 512){ sab[t] = qb[t]; cab[t] = ckb[t]; cab[512 + t] = cvb[t]; }
  else if (t < 1024){ sab[t] = kb[t - 512]; }
  else if (t < 1536){ sab[t] = vb[t - 1024]; }
}

// ---------------- LayerNorm: fp32 [rows,512] -> bf16; one row per WAVE (64 lanes x 32B) ----------------
__global__ __launch_bounds__(256) void ln_kernel(const float* __restrict__ in, bf16* __restrict__ out,
                                                 const float* __restrict__ g, const float* __restrict__ b){
  int row = blockIdx.x * 4 + (threadIdx.x >> 6);
  int lane = threadIdx.x & 63;
  const float* r = in + (size_t)row * 512 + lane * 8;
  float4 v0 = *(const float4*)r;
  float4 v1 = *(const float4*)(r + 4);
  float f[8] = {v0.x, v0.y, v0.z, v0.w, v1.x, v1.y, v1.z, v1.w};
  float s = 0.0f, s2 = 0.0f;
  #pragma unroll
  for (int j = 0; j < 8; ++j){ s += f[j]; s2 += f[j] * f[j]; }
  #pragma unroll
  for (int o = 1; o < 64; o <<= 1){ s += __shfl_xor(s, o); s2 += __shfl_xor(s2, o); }
  float mu = s * (1.0f / 512.0f);
  float var = fmaxf(s2 * (1.0f / 512.0f) - mu * mu, 0.0f);
  float rstd = rsqrtf(var + 1e-5f);
  int c = lane * 8;
  s8 o;
  #pragma unroll
  for (int j = 0; j < 8; ++j)
    ((bf16*)&o)[j] = f2bf((f[j] - mu) * rstd * g[c + j] + b[c + j]);
  *(s8*)&out[(size_t)row * 512 + c] = o;
}

// ---------- Stylization LN: bf16 y [rows,512], e fp32 [B,1024] -> bf16 silu(adaLN); row per wave ----------
__global__ __launch_bounds__(256) void styl_ln_kernel(const bf16* __restrict__ in, const float* __restrict__ e,
                                                      const float* __restrict__ g, const float* __restrict__ b,
                                                      bf16* __restrict__ out, int T){
  int row = blockIdx.x * 4 + (threadIdx.x >> 6);
  int lane = threadIdx.x & 63;
  int bidx = row / T;
  int c = lane * 8;
  s8 hv = *(const s8*)&in[(size_t)row * 512 + c];
  float f[8];
  float s = 0.0f, s2 = 0.0f;
  #pragma unroll
  for (int j = 0; j < 8; ++j){
    f[j] = bf2f(((const bf16*)&hv)[j]);
    s += f[j]; s2 += f[j] * f[j];
  }
  #pragma unroll
  for (int o = 1; o < 64; o <<= 1){ s += __shfl_xor(s, o); s2 += __shfl_xor(s2, o); }
  float mu = s * (1.0f / 512.0f);
  float var = fmaxf(s2 * (1.0f / 512.0f) - mu * mu, 0.0f);
  float rstd = rsqrtf(var + 1e-5f);
  const float* eb = e + (size_t)bidx * 1024;
  s8 o;
  #pragma unroll
  for (int j = 0; j < 8; ++j){
    float h = (f[j] - mu) * rstd * g[c + j] + b[c + j];
    h = h * (1.0f + eb[c + j]) + eb[512 + c + j];
    ((bf16*)&o)[j] = f2bf(silu_f(h));
  }
  *(s8*)&out[(size_t)row * 512 + c] = o;
}

// ---------- fused partial: att_part[c,b,h,d,l] = sum_{t in chunk c} mask_t*exp(k[t,d]) * v[t,l] ----------
__global__ __launch_bounds__(256) void kv_outer(const bf16* __restrict__ k, const bf16* __restrict__ v,
                                                const float* __restrict__ mask,
                                                float* __restrict__ att_part, float* __restrict__ den_part,
                                                int T, int ld, int Tc){
  int bh = blockIdx.x;            // b*8+h
  int b = bh >> 3, h = bh & 7;
  int chunk = blockIdx.y;
  int t_begin = chunk * Tc;
  __shared__ float kexp[64][64];
  __shared__ bf16 vb[64][64];
  int tid = threadIdx.x;
  int lg = tid & 15, tg = tid >> 4;
  int d0 = tg * 4, l0 = lg * 4;
  const float* mrow = mask ? (mask + (size_t)b * T) : nullptr;
  float acc[4][4] = {};
  float sden[4] = {0.0f, 0.0f, 0.0f, 0.0f};
  for (int tcb = t_begin; tcb < t_begin + Tc; tcb += 64){
    __syncthreads();
    #pragma unroll
    for (int i = 0; i < 2; ++i){
      int rr = (tid >> 3) + i * 32;
      int cc = (tid & 7) * 8;
      size_t goff = ((size_t)(b * T + tcb + rr)) * ld + h * 64 + cc;
      s8 kv8 = *(const s8*)&k[goff];
      *(s8*)&vb[rr][cc] = *(const s8*)&v[goff];
      float mk = mrow ? mrow[tcb + rr] : 1.0f;
      float4 e0, e1;
      e0.x = mk * __expf(bf2f(((const bf16*)&kv8)[0]));
      e0.y = mk * __expf(bf2f(((const bf16*)&kv8)[1]));
      e0.z = mk * __expf(bf2f(((const bf16*)&kv8)[2]));
      e0.w = mk * __expf(bf2f(((const bf16*)&kv8)[3]));
      e1.x = mk * __expf(bf2f(((const bf16*)&kv8)[4]));
      e1.y = mk * __expf(bf2f(((const bf16*)&kv8)[5]));
      e1.z = mk * __expf(bf2f(((const bf16*)&kv8)[6]));
      e1.w = mk * __expf(bf2f(((const bf16*)&kv8)[7]));
      *(float4*)&kexp[rr][cc]     = e0;
      *(float4*)&kexp[rr][cc + 4] = e1;
    }
    __syncthreads();
    for (int tt = 0; tt < 64; ++tt){
      float4 kf = *(const float4*)&kexp[tt][d0];
      float kk[4] = {kf.x, kf.y, kf.z, kf.w};
      h4 vv4 = *(const h4*)&vb[tt][l0];     // explicit 8B vector LDS read
      float vv[4];
      #pragma unroll
      for (int j = 0; j < 4; ++j) vv[j] = bf2f(((const bf16*)&vv4)[j]);
      #pragma unroll
      for (int a = 0; a < 4; ++a){
        sden[a] += kk[a];
        #pragma unroll
        for (int c2 = 0; c2 < 4; ++c2) acc[a][c2] += kk[a] * vv[c2];
      }
    }
  }
  size_t base = ((size_t)(chunk * 256 + bh)) * 4096;
  #pragma unroll
  for (int a = 0; a < 4; ++a)
    #pragma unroll
    for (int c2 = 0; c2 < 4; ++c2) att_part[base + (size_t)(d0 + a) * 64 + l0 + c2] = acc[a][c2];
  if (lg == 0){
    size_t dbase = ((size_t)(chunk * 256 + bh)) * 64;
    #pragma unroll
    for (int a = 0; a < 4; ++a) den_part[dbase + d0 + a] = sden[a];
  }
}

// ---------- att[b,h,d,l] = (sum_c att_part) / (sum_c den_part) ----------
__global__ __launch_bounds__(256) void kv_reduce(const float* __restrict__ att_part,
                                                 const float* __restrict__ den_part,
                                                 float* __restrict__ att, int nchunk){
  int bh = blockIdx.x, tid = threadIdx.x;
  __shared__ float dinv[64];
  if (tid < 64){
    float d = 0.0f;
    for (int c = 0; c < nchunk; ++c) d += den_part[((size_t)(c * 256 + bh)) * 64 + tid];
    dinv[tid] = 1.0f / d;
  }
  __syncthreads();
  #pragma unroll
  for (int i = 0; i < 16; ++i){
    int e = i * 256 + tid;
    float s = 0.0f;
    for (int c = 0; c < nchunk; ++c) s += att_part[((size_t)(c * 256 + bh)) * 4096 + e];
    att[(size_t)bh * 4096 + e] = s * dinv[e >> 6];
  }
}

// ---------- y[b,t,h,l] = sum_d softmax_feat(q)[b,t,h,d] * att[b,h,d,l] ----------
// dd-loop blocked by 8: qv rows hoisted via ds_read_b128 (swizzle XOR acts on bits>=3,
// so 8 consecutive dd of one row are contiguous at base d8 ^ ((row&7)<<3)).
__global__ __launch_bounds__(256) void q_att(const bf16* __restrict__ q, const float* __restrict__ att,
                                             bf16* __restrict__ y, int T, int ldq){
  int ntc = T >> 6;
  int idx = blockIdx.x;
  int tcb = idx % ntc; int h = (idx / ntc) & 7; int b = idx / (ntc * 8);
  __shared__ float ab[64][64];
  __shared__ bf16 qb[64][64];   // XOR-swizzled columns: c' = c ^ ((row&7)<<3)
  int tid = threadIdx.x;
  #pragma unroll
  for (int i = 0; i < 4; ++i){
    int e = i * 1024 + tid * 4;
    *(float4*)&ab[e >> 6][e & 63] = *(const float4*)&att[((size_t)(b * 8 + h)) * 4096 + e];
  }
  #pragma unroll
  for (int i = 0; i < 2; ++i){
    int rr = (tid >> 3) + i * 32;
    int cc = (tid & 7) * 8;
    s8 v = *(const s8*)&q[((size_t)(b * T + tcb * 64 + rr)) * ldq + h * 64 + cc];
    float f[8];
    #pragma unroll
    for (int j = 0; j < 8; ++j) f[j] = bf2f(((const bf16*)&v)[j]);
    float m = f[0];
    #pragma unroll
    for (int j = 1; j < 8; ++j) m = fmaxf(m, f[j]);
    m = fmaxf(m, __shfl_xor(m, 1));
    m = fmaxf(m, __shfl_xor(m, 2));
    m = fmaxf(m, __shfl_xor(m, 4));
    float s = 0.0f;
    #pragma unroll
    for (int j = 0; j < 8; ++j){ f[j] = __expf(f[j] - m); s += f[j]; }
    s += __shfl_xor(s, 1);
    s += __shfl_xor(s, 2);
    s += __shfl_xor(s, 4);
    float inv = 1.0f / s;
    s8 o;
    #pragma unroll
    for (int j = 0; j < 8; ++j) ((bf16*)&o)[j] = f2bf(f[j] * inv);
    *(s8*)&qb[rr][cc ^ ((rr & 7) << 3)] = o;
  }
  __syncthreads();
  int lg = tid & 15, tg = tid >> 4;
  int t0 = tg * 4, l0 = lg * 4;
  float acc[4][4] = {};
  for (int d8 = 0; d8 < 64; d8 += 8){
    s8 qrow[4];
    #pragma unroll
    for (int j = 0; j < 4; ++j){
      int row = t0 + j;
      qrow[j] = *(const s8*)&qb[row][d8 ^ ((row & 7) << 3)];
    }
    #pragma unroll
    for (int e = 0; e < 8; ++e){
      float4 av4 = *(const float4*)&ab[d8 + e][l0];
      float av[4] = {av4.x, av4.y, av4.z, av4.w};
      #pragma unroll
      for (int a = 0; a < 4; ++a){
        float qv = bf2f(((const bf16*)&qrow[a])[e]);
        #pragma unroll
        for (int c2 = 0; c2 < 4; ++c2) acc[a][c2] += qv * av[c2];
      }
    }
  }
  #pragma unroll
  for (int a = 0; a < 4; ++a)
    #pragma unroll
    for (int c2 = 0; c2 < 4; ++c2)
      y[((size_t)(b * T + tcb * 64 + t0 + a)) * 512 + h * 64 + l0 + c2] = f2bf(acc[a][c2]);
}

// ---------- e_all[which][b][col] = silu(emb[b]) @ W_which + b_which ; [3,32,1024] fp32 ----------
__global__ __launch_bounds__(256) void emb_gemm(const float* __restrict__ emb,
    const float* __restrict__ w0, const float* __restrict__ b0,
    const float* __restrict__ w1, const float* __restrict__ b1,
    const float* __restrict__ w2, const float* __restrict__ b2,
    float* __restrict__ e_all){
  int col = blockIdx.x * 256 + threadIdx.x;
  int b = blockIdx.y, which = blockIdx.z;
  const float* W  = (which == 0) ? w0 : (which == 1 ? w1 : w2);
  const float* bb = (which == 0) ? b0 : (which == 1 ? b1 : b2);
  __shared__ float s[512];
  for (int i = threadIdx.x; i < 512; i += 256){ float v = emb[b * 512 + i]; s[i] = silu_f(v); }
  __syncthreads();
  float acc = bb[col];
  for (int kk = 0; kk < 512; ++kk) acc += s[kk] * W[(size_t)kk * 1024 + col];
  e_all[((size_t)which * 32 + b) * 1024 + col] = acc;
}

// ---------------- bf16 MFMA GEMM, HYBRID epilogue (round-12 proven form) ----------------
// SW = (EPI in {3,4,5}): swapped mfma operands -> lane holds 4 consecutive COLS ->
//   float4 RMW epilogue (measured win for fp32 read-modify-write, round 11).
// !SW (EPI 0,2,6): original operand order -> lane-contiguous scalar bf16 stores
//   (measured win for pure bf16 streams, round 9: FFN1/FFN2 112 vs 123 us).
// NOTE: out/out2 must never alias A (cross-block WAR race — round-10 lesson).
// EPI: 0 = bf16 store (+bias); 2 = bf16 store gelu(+bias);
//      3 = fp32 out += (+bias);  4 = fp32 out = extra + (+bias);
//      5 = fp32 out += (+bias), AND bf16 copy of new value to out2;
//      6 = bf16 store (+bias), times extra[row] for cols >= 1024 (fused SA QKV)
template<int EPI>
__global__ __launch_bounds__(256, 2) void gemm_bt(
    const bf16* __restrict__ A, const bf16* __restrict__ BT,
    const float* __restrict__ bias, void* __restrict__ out,
    const float* __restrict__ extra, void* __restrict__ out2, int M, int N, int K){
  constexpr bool SW = (EPI == 3 || EPI == 4 || EPI == 5);
  __shared__ __align__(16) bf16 As[2][128 * 32];
  __shared__ __align__(16) bf16 Bs[2][128 * 32];
  int tid = threadIdx.x;
  int w = tid >> 6, lane = tid & 63;
  int wr = w >> 1, wc = w & 1;
  // ---- XCD-aware bijective block swizzle (T1, m204 form) ----
  int nwg = gridDim.x * gridDim.y;
  int lin = blockIdx.y * gridDim.x + blockIdx.x;
  int xcd = lin & 7, sidx = lin >> 3;
  int q8 = nwg >> 3, r8 = nwg & 7;
  int wg = (xcd < r8 ? xcd * (q8 + 1) : r8 * (q8 + 1) + (xcd - r8) * q8) + sidx;
  int bn = wg % gridDim.x, bm = wg / gridDim.x;

  const bf16* Ab = A  + (size_t)bm * 128 * K;
  const bf16* Bb = BT + (size_t)bn * 128 * K;

  int srow = tid >> 2;            // tid*8 / 32
  int scol = (tid & 3) * 8;

  auto stage = [&](int buf, int k0){
    #pragma unroll
    for (int i = 0; i < 2; ++i){
      const bf16* ga = Ab + (size_t)(srow + i * 64) * K + k0 + scol;
      const bf16* gb = Bb + (size_t)(srow + i * 64) * K + k0 + scol;
      bf16* la = &As[buf][i * 2048 + w * 512];
      bf16* lb = &Bs[buf][i * 2048 + w * 512];
      __builtin_amdgcn_global_load_lds((const __attribute__((address_space(1))) void*)ga,
                                       (__attribute__((address_space(3))) void*)la, 16, 0, 0);
      __builtin_amdgcn_global_load_lds((const __attribute__((address_space(1))) void*)gb,
                                       (__attribute__((address_space(3))) void*)lb, 16, 0, 0);
    }
  };

  f4 acc[4][4];
  #pragma unroll
  for (int m = 0; m < 4; ++m)
    #pragma unroll
    for (int n = 0; n < 4; ++n)
      #pragma unroll
      for (int j = 0; j < 4; ++j) acc[m][n][j] = 0.0f;

  int nt = K >> 5;
  int arow = lane & 15;
  int koff = (lane >> 4) * 8;

  stage(0, 0);
  __syncthreads();
  int cur = 0;
  for (int t = 0; t < nt; ++t){
    if (t + 1 < nt) stage(cur ^ 1, (t + 1) * 32);
    s8 af[4], bfv[4];
    #pragma unroll
    for (int m = 0; m < 4; ++m)
      af[m] = *(const s8*)&As[cur][(wr * 64 + m * 16 + arow) * 32 + koff];
    #pragma unroll
    for (int n = 0; n < 4; ++n)
      bfv[n] = *(const s8*)&Bs[cur][(wc * 64 + n * 16 + arow) * 32 + koff];
    #pragma unroll
    for (int m = 0; m < 4; ++m)
      #pragma unroll
      for (int n = 0; n < 4; ++n){
        if constexpr (SW)
          acc[m][n] = __builtin_amdgcn_mfma_f32_16x16x32_bf16(bfv[n], af[m], acc[m][n], 0, 0, 0);
        else
          acc[m][n] = __builtin_amdgcn_mfma_f32_16x16x32_bf16(af[m], bfv[n], acc[m][n], 0, 0, 0);
      }
    __syncthreads();
    cur ^= 1;
  }

  if constexpr (SW){
    // swapped layout: row = rbase + m*16 (fixed/lane), col = cbase + n*16 + j (4 consecutive)
    int rbase = bm * 128 + wr * 64 + (lane & 15);
    int cbase = bn * 128 + wc * 64 + (lane >> 4) * 4;
    #pragma unroll
    for (int m = 0; m < 4; ++m){
      int row = rbase + m * 16;
      #pragma unroll
      for (int n = 0; n < 4; ++n){
        int col = cbase + n * 16;
        float4 bv = *(const float4*)&bias[col];
        float v0 = acc[m][n][0] + bv.x;
        float v1 = acc[m][n][1] + bv.y;
        float v2 = acc[m][n][2] + bv.z;
        float v3 = acc[m][n][3] + bv.w;
        size_t oi = (size_t)row * N + col;
        if (EPI == 3){
          float4* po = (float4*)&((float*)out)[oi];
          float4 c = *po;
          c.x += v0; c.y += v1; c.z += v2; c.w += v3;
          *po = c;
        } else if (EPI == 4){
          float4 e = *(const float4*)&extra[oi];
          float4 r = {e.x + v0, e.y + v1, e.z + v2, e.w + v3};
          *(float4*)&((float*)out)[oi] = r;
        } else {
          float4* po = (float4*)&((float*)out)[oi];
          float4 c = *po;
          c.x += v0; c.y += v1; c.z += v2; c.w += v3;
          *po = c;
          h4 o;
          ((bf16*)&o)[0] = f2bf(c.x); ((bf16*)&o)[1] = f2bf(c.y);
          ((bf16*)&o)[2] = f2bf(c.z); ((bf16*)&o)[3] = f2bf(c.w);
          *(h4*)&((bf16*)out2)[oi] = o;
        }
      }
    }
  } else {
    // original layout: row = r0 + m*16 + j, col = c0 + n*16 (lane-contiguous cols)
    int r0 = bm * 128 + wr * 64 + (lane >> 4) * 4;
    int c0 = bn * 128 + wc * 64 + (lane & 15);
    #pragma unroll
    for (int m = 0; m < 4; ++m){
      #pragma unroll
      for (int n = 0; n < 4; ++n){
        int col = c0 + n * 16;
        float bv = bias[col];
        #pragma unroll
        for (int j = 0; j < 4; ++j){
          int row = r0 + m * 16 + j;
          float v = acc[m][n][j] + bv;
          size_t oi = (size_t)row * N + col;
          if (EPI == 0){
            ((bf16*)out)[oi] = f2bf(v);
          } else if (EPI == 2){
            ((bf16*)out)[oi] = f2bf(gelu_f(v));
          } else { // EPI 6: fused QKV, mask V block (cols >= 1024)
            float sc = (col >= 1024) ? extra[row] : 1.0f;
            ((bf16*)out)[oi] = f2bf(v * sc);
          }
        }
      }
    }
  }
}

// =====================================================================================
extern "C" void kernel_launch(void* const* d_in, const int* in_sizes, int n_in,
                              void* d_out, int out_size, void* d_ws, size_t ws_size,
                              hipStream_t stream){
  const float* x    = (const float*)d_in[0];
  const float* xf   = (const float*)d_in[1];
  const float* emb  = (const float*)d_in[2];
  const float* mask = (const float*)d_in[3];
  const float* P[40];
  for (int j = 0; j < 40; ++j) P[j] = (const float*)d_in[4 + j];
  enum { SA_NG, SA_NB, SA_QW, SA_QB, SA_KW, SA_KB, SA_VW, SA_VB, SA_EW, SA_EB, SA_PG, SA_PB, SA_OW, SA_OB,
         CA_NG, CA_NB, CA_TG, CA_TB, CA_QW, CA_QB, CA_KW, CA_KB, CA_VW, CA_VB, CA_EW, CA_EB, CA_PG, CA_PB, CA_OW, CA_OB,
         F_W1, F_B1, F_W2, F_B2, F_EW, F_EB, F_PG, F_PB, F_OW, F_OB };

  char* wp = (char*)d_ws;
  auto alloc = [&](size_t bytes){ void* p = (void*)wp; wp += (bytes + 255) & ~(size_t)255; return p; };

  const size_t SQ = (size_t)512 * 512 * 2;       // 512x512 bf16
  bf16* WT_saqkv = (bf16*)alloc(3 * SQ);          // [1536,512]
  bf16* WT_saout = (bf16*)alloc(SQ);
  bf16* WT_caq   = (bf16*)alloc(SQ);
  bf16* WT_cakv  = (bf16*)alloc(2 * SQ);          // [1024,512]
  bf16* WT_caout = (bf16*)alloc(SQ);
  bf16* WT_f1    = (bf16*)alloc((size_t)2048 * 512 * 2);
  bf16* WT_f2    = (bf16*)alloc((size_t)512 * 2048 * 2);
  bf16* WT_fout  = (bf16*)alloc(SQ);
  float* cat_sab = (float*)alloc(1536 * 4);
  float* cat_cab = (float*)alloc(1024 * 4);
  float* e_all   = (float*)alloc((size_t)3 * 32 * 1024 * 4);

  const size_t BTD2 = (size_t)32768 * 512 * 2;    // 32 MB (bf16 [B*T, D])
  bf16* bxn  = (bf16*)alloc(BTD2);                // \ contiguous 128MB span:
  bf16* bqkv = (bf16*)alloc(3 * BTD2);            // /  reused as FFN hidden
  bf16* by   = (bf16*)alloc(BTD2);
  bf16* bs   = (bf16*)alloc(BTD2);
  bf16* btn  = (bf16*)alloc((size_t)8192 * 512 * 2);
  float* att_part = (float*)alloc((size_t)4 * 256 * 4096 * 4);   // up to 4 chunks
  float* den_part = (float*)alloc((size_t)4 * 256 * 64 * 4);
  float* batt = (float*)alloc((size_t)256 * 4096 * 4);
  bf16* bh1 = bxn;                                // FFN hidden [32768,2048] overlays bxn+bqkv
  bf16* bq_ca  = bqkv;                            // CA q  [32768,512]
  bf16* bkv_ca = bqkv + BTD2 / 2;                 // CA kv [8192,1024]

  // ---- single batched transpose dispatch (11 matrices) ----
  TPack tp;
  auto set = [&](int i, const float* s, bf16* d, int K, int N){
    tp.d[i].src = s; tp.d[i].dst = d; tp.d[i].K = K; tp.d[i].N = N;
    tp.d[i].tiles = (K >> 5) * (N >> 5);
  };
  set(0,  P[SA_QW], WT_saqkv,              512, 512);
  set(1,  P[SA_KW], WT_saqkv + 512 * 512,  512, 512);
  set(2,  P[SA_VW], WT_saqkv + 1024 * 512, 512, 512);
  set(3,  P[SA_OW], WT_saout,              512, 512);
  set(4,  P[CA_QW], WT_caq,                512, 512);
  set(5,  P[CA_KW], WT_cakv,               512, 512);
  set(6,  P[CA_VW], WT_cakv + 512 * 512,   512, 512);
  set(7,  P[CA_OW], WT_caout,              512, 512);
  set(8,  P[F_OW],  WT_fout,               512, 512);
  set(9,  P[F_W1],  WT_f1,                 512, 2048);
  set(10, P[F_W2],  WT_f2,                 2048, 512);
  int total_tiles = 9 * 256 + 1024 + 1024;   // 4352
  transpose_all<<<total_tiles, dim3(32, 8), 0, stream>>>(tp);

  concat_bias<<<6, 256, 0, stream>>>(P[SA_QB], P[SA_KB], P[SA_VB], P[CA_KB], P[CA_VB], cat_sab, cat_cab);

  emb_gemm<<<dim3(4, 32, 3), 256, 0, stream>>>(emb, P[SA_EW], P[SA_EB], P[CA_EW], P[CA_EB],
                                               P[F_EW], P[F_EB], e_all);

  dim3 g512(4, 256);   // N=512, M=32768

  // ---------------- self-attention ----------------
  ln_kernel<<<8192, 256, 0, stream>>>(x, bxn, P[SA_NG], P[SA_NB]);
  gemm_bt<6><<<dim3(12, 256), 256, 0, stream>>>(bxn, WT_saqkv, cat_sab, bqkv, mask, nullptr, 32768, 1536, 512);
  kv_outer<<<dim3(256, 4), 256, 0, stream>>>(bqkv + 512, bqkv + 1024, mask, att_part, den_part, 1024, 1536, 256);
  kv_reduce<<<256, 256, 0, stream>>>(att_part, den_part, batt, 4);
  q_att<<<4096, 256, 0, stream>>>(bqkv, batt, by, 1024, 1536);
  styl_ln_kernel<<<8192, 256, 0, stream>>>(by, e_all, P[SA_PG], P[SA_PB], bs, 1024);
  gemm_bt<4><<<g512, 256, 0, stream>>>(bs, WT_saout, P[SA_OB], d_out, x, nullptr, 32768, 512, 512);

  // ---------------- cross-attention ----------------
  ln_kernel<<<8192, 256, 0, stream>>>((const float*)d_out, bxn, P[CA_NG], P[CA_NB]);
  ln_kernel<<<2048, 256, 0, stream>>>(xf, btn, P[CA_TG], P[CA_TB]);
  gemm_bt<0><<<g512, 256, 0, stream>>>(bxn, WT_caq, P[CA_QB], bq_ca, nullptr, nullptr, 32768, 512, 512);
  gemm_bt<0><<<dim3(8, 64), 256, 0, stream>>>(btn, WT_cakv, cat_cab, bkv_ca, nullptr, nullptr, 8192, 1024, 512);
  kv_outer<<<dim3(256, 2), 256, 0, stream>>>(bkv_ca, bkv_ca + 512, nullptr, att_part, den_part, 256, 1024, 128);
  kv_reduce<<<256, 256, 0, stream>>>(att_part, den_part, batt, 2);
  q_att<<<4096, 256, 0, stream>>>(bq_ca, batt, by, 1024, 512);
  styl_ln_kernel<<<8192, 256, 0, stream>>>(by, e_all + 32 * 1024, P[CA_PG], P[CA_PB], bs, 1024);
  // out2 = by (NOT bs): A and out2 must not alias (cross-block WAR race)
  gemm_bt<5><<<g512, 256, 0, stream>>>(bs, WT_caout, P[CA_OB], d_out, nullptr, by, 32768, 512, 512);

  // ---------------- FFN ----------------
  gemm_bt<2><<<dim3(16, 256), 256, 0, stream>>>(by, WT_f1, P[F_B1], bh1, nullptr, nullptr, 32768, 2048, 512);
  gemm_bt<0><<<dim3(4, 256), 256, 0, stream>>>(bh1, WT_f2, P[F_B2], bs, nullptr, nullptr, 32768, 512, 2048);
  styl_ln_kernel<<<8192, 256, 0, stream>>>(bs, e_all + 2 * 32 * 1024, P[F_PG], P[F_PB], by, 1024);
  gemm_bt<3><<<g512, 256, 0, stream>>>(by, WT_fout, P[F_OB], d_out, nullptr, nullptr, 32768, 512, 512);
}

// Round 18
// 731.271 us; speedup vs baseline: 1.1676x; 1.0650x over previous
//
#include <hip/hip_runtime.h>
#include <hip/hip_bf16.h>
#include <math.h>

typedef __hip_bfloat16 bf16;
typedef __hip_bfloat162 bf16x2;
using s8 = __attribute__((ext_vector_type(8))) short;
using h4 = __attribute__((ext_vector_type(4))) short;
using f4 = __attribute__((ext_vector_type(4))) float;

#define DEV __device__ __forceinline__
DEV float bf2f(bf16 h){ return __bfloat162float(h); }
DEV bf16  f2bf(float f){ return __float2bfloat16(f); }
DEV float silu_f(float x){ return x / (1.0f + __expf(-x)); }
// tanh-form gelu: x * sigmoid(1.59577*(x + 0.044715 x^3)); max |diff| vs erf-gelu ~3e-3
DEV float gelu_f(float x){
  float z = 1.5957691216f * x * (1.0f + 0.044715f * x * x);
  return x / (1.0f + __expf(-z));
}

// ---------------- batched weight transpose: fp32 [K,N] -> bf16 [N,K], 11 matrices ----------------
struct TDesc { const float* src; bf16* dst; int K; int N; int tiles; };
struct TPack { TDesc d[11]; };
__global__ __launch_bounds__(256) void transpose_all(TPack p){
  int tile = blockIdx.x;
  int i = 0, base = 0;
  while (i < 10 && tile >= base + p.d[i].tiles){ base += p.d[i].tiles; ++i; }
  int local = tile - base;
  const float* in = p.d[i].src;
  bf16* out = p.d[i].dst;
  int K = p.d[i].K, N = p.d[i].N;
  int ntx = N >> 5;
  int n0 = (local % ntx) * 32, k0 = (local / ntx) * 32;
  __shared__ float t[32][33];
  int tx = threadIdx.x, ty = threadIdx.y; // block (32,8)
  for (int r = ty; r < 32; r += 8) t[r][tx] = in[(size_t)(k0 + r) * N + n0 + tx];
  __syncthreads();
  for (int r = ty; r < 32; r += 8) out[(size_t)(n0 + r) * K + k0 + tx] = f2bf(t[tx][r]);
}

// ---------------- bias concat: sab=[qb|kb|vb], cab=[ckb|cvb] ----------------
__global__ __launch_bounds__(256) void concat_bias(const float* __restrict__ qb, const float* __restrict__ kb,
                                                   const float* __restrict__ vb, const float* __restrict__ ckb,
                                                   const float* __restrict__ cvb,
                                                   float* __restrict__ sab, float* __restrict__ cab){
  int t = blockIdx.x * 256 + threadIdx.x;
  if (t < 512){ sab[t] = qb[t]; cab[t] = ckb[t]; cab[512 + t] = cvb[t]; }
  else if (t < 1024){ sab[t] = kb[t - 512]; }
  else if (t < 1536){ sab[t] = vb[t - 1024]; }
}

// ---------------- LayerNorm: fp32 [rows,512] -> bf16; one row per WAVE (64 lanes x 32B) ----------------
__global__ __launch_bounds__(256) void ln_kernel(const float* __restrict__ in, bf16* __restrict__ out,
                                                 const float* __restrict__ g, const float* __restrict__ b){
  int row = blockIdx.x * 4 + (threadIdx.x >> 6);
  int lane = threadIdx.x & 63;
  const float* r = in + (size_t)row * 512 + lane * 8;
  float4 v0 = *(const float4*)r;
  float4 v1 = *(const float4*)(r + 4);
  float f[8] = {v0.x, v0.y, v0.z, v0.w, v1.x, v1.y, v1.z, v1.w};
  float s = 0.0f, s2 = 0.0f;
  #pragma unroll
  for (int j = 0; j < 8; ++j){ s += f[j]; s2 += f[j] * f[j]; }
  #pragma unroll
  for (int o = 1; o < 64; o <<= 1){ s += __shfl_xor(s, o); s2 += __shfl_xor(s2, o); }
  float mu = s * (1.0f / 512.0f);
  float var = fmaxf(s2 * (1.0f / 512.0f) - mu * mu, 0.0f);
  float rstd = rsqrtf(var + 1e-5f);
  int c = lane * 8;
  s8 o;
  #pragma unroll
  for (int j = 0; j < 8; ++j)
    ((bf16*)&o)[j] = f2bf((f[j] - mu) * rstd * g[c + j] + b[c + j]);
  *(s8*)&out[(size_t)row * 512 + c] = o;
}

// ---------------- LayerNorm: bf16 [rows,512] -> bf16; one row per WAVE ----------------
__global__ __launch_bounds__(256) void ln_bf16_kernel(const bf16* __restrict__ in, bf16* __restrict__ out,
                                                      const float* __restrict__ g, const float* __restrict__ b){
  int row = blockIdx.x * 4 + (threadIdx.x >> 6);
  int lane = threadIdx.x & 63;
  int c = lane * 8;
  s8 hv = *(const s8*)&in[(size_t)row * 512 + c];
  float f[8];
  float s = 0.0f, s2 = 0.0f;
  #pragma unroll
  for (int j = 0; j < 8; ++j){
    f[j] = bf2f(((const bf16*)&hv)[j]);
    s += f[j]; s2 += f[j] * f[j];
  }
  #pragma unroll
  for (int o = 1; o < 64; o <<= 1){ s += __shfl_xor(s, o); s2 += __shfl_xor(s2, o); }
  float mu = s * (1.0f / 512.0f);
  float var = fmaxf(s2 * (1.0f / 512.0f) - mu * mu, 0.0f);
  float rstd = rsqrtf(var + 1e-5f);
  s8 o;
  #pragma unroll
  for (int j = 0; j < 8; ++j)
    ((bf16*)&o)[j] = f2bf((f[j] - mu) * rstd * g[c + j] + b[c + j]);
  *(s8*)&out[(size_t)row * 512 + c] = o;
}

// ---------- Stylization LN: bf16 y [rows,512], e fp32 [B,1024] -> bf16 silu(adaLN); row per wave ----------
__global__ __launch_bounds__(256) void styl_ln_kernel(const bf16* __restrict__ in, const float* __restrict__ e,
                                                      const float* __restrict__ g, const float* __restrict__ b,
                                                      bf16* __restrict__ out, int T){
  int row = blockIdx.x * 4 + (threadIdx.x >> 6);
  int lane = threadIdx.x & 63;
  int bidx = row / T;
  int c = lane * 8;
  s8 hv = *(const s8*)&in[(size_t)row * 512 + c];
  float f[8];
  float s = 0.0f, s2 = 0.0f;
  #pragma unroll
  for (int j = 0; j < 8; ++j){
    f[j] = bf2f(((const bf16*)&hv)[j]);
    s += f[j]; s2 += f[j] * f[j];
  }
  #pragma unroll
  for (int o = 1; o < 64; o <<= 1){ s += __shfl_xor(s, o); s2 += __shfl_xor(s2, o); }
  float mu = s * (1.0f / 512.0f);
  float var = fmaxf(s2 * (1.0f / 512.0f) - mu * mu, 0.0f);
  float rstd = rsqrtf(var + 1e-5f);
  const float* eb = e + (size_t)bidx * 1024;
  s8 o;
  #pragma unroll
  for (int j = 0; j < 8; ++j){
    float h = (f[j] - mu) * rstd * g[c + j] + b[c + j];
    h = h * (1.0f + eb[c + j]) + eb[512 + c + j];
    ((bf16*)&o)[j] = f2bf(silu_f(h));
  }
  *(s8*)&out[(size_t)row * 512 + c] = o;
}

// ---------- fused partial: att_part[c,b,h,d,l] = sum_{t in chunk c} mask_t*exp(k[t,d]) * v[t,l] ----------
__global__ __launch_bounds__(256) void kv_outer(const bf16* __restrict__ k, const bf16* __restrict__ v,
                                                const float* __restrict__ mask,
                                                float* __restrict__ att_part, float* __restrict__ den_part,
                                                int T, int ld, int Tc){
  int bh = blockIdx.x;            // b*8+h
  int b = bh >> 3, h = bh & 7;
  int chunk = blockIdx.y;
  int t_begin = chunk * Tc;
  __shared__ float kexp[64][64];
  __shared__ bf16 vb[64][64];
  int tid = threadIdx.x;
  int lg = tid & 15, tg = tid >> 4;
  int d0 = tg * 4, l0 = lg * 4;
  const float* mrow = mask ? (mask + (size_t)b * T) : nullptr;
  float acc[4][4] = {};
  float sden[4] = {0.0f, 0.0f, 0.0f, 0.0f};
  for (int tcb = t_begin; tcb < t_begin + Tc; tcb += 64){
    __syncthreads();
    #pragma unroll
    for (int i = 0; i < 2; ++i){
      int rr = (tid >> 3) + i * 32;
      int cc = (tid & 7) * 8;
      size_t goff = ((size_t)(b * T + tcb + rr)) * ld + h * 64 + cc;
      s8 kv8 = *(const s8*)&k[goff];
      *(s8*)&vb[rr][cc] = *(const s8*)&v[goff];
      float mk = mrow ? mrow[tcb + rr] : 1.0f;
      float4 e0, e1;
      e0.x = mk * __expf(bf2f(((const bf16*)&kv8)[0]));
      e0.y = mk * __expf(bf2f(((const bf16*)&kv8)[1]));
      e0.z = mk * __expf(bf2f(((const bf16*)&kv8)[2]));
      e0.w = mk * __expf(bf2f(((const bf16*)&kv8)[3]));
      e1.x = mk * __expf(bf2f(((const bf16*)&kv8)[4]));
      e1.y = mk * __expf(bf2f(((const bf16*)&kv8)[5]));
      e1.z = mk * __expf(bf2f(((const bf16*)&kv8)[6]));
      e1.w = mk * __expf(bf2f(((const bf16*)&kv8)[7]));
      *(float4*)&kexp[rr][cc]     = e0;
      *(float4*)&kexp[rr][cc + 4] = e1;
    }
    __syncthreads();
    for (int tt = 0; tt < 64; ++tt){
      float4 kf = *(const float4*)&kexp[tt][d0];
      float kk[4] = {kf.x, kf.y, kf.z, kf.w};
      h4 vv4 = *(const h4*)&vb[tt][l0];     // explicit 8B vector LDS read
      float vv[4];
      #pragma unroll
      for (int j = 0; j < 4; ++j) vv[j] = bf2f(((const bf16*)&vv4)[j]);
      #pragma unroll
      for (int a = 0; a < 4; ++a){
        sden[a] += kk[a];
        #pragma unroll
        for (int c2 = 0; c2 < 4; ++c2) acc[a][c2] += kk[a] * vv[c2];
      }
    }
  }
  size_t base = ((size_t)(chunk * 256 + bh)) * 4096;
  #pragma unroll
  for (int a = 0; a < 4; ++a)
    #pragma unroll
    for (int c2 = 0; c2 < 4; ++c2) att_part[base + (size_t)(d0 + a) * 64 + l0 + c2] = acc[a][c2];
  if (lg == 0){
    size_t dbase = ((size_t)(chunk * 256 + bh)) * 64;
    #pragma unroll
    for (int a = 0; a < 4; ++a) den_part[dbase + d0 + a] = sden[a];
  }
}

// ---------- att[b,h,d,l] = (sum_c att_part) / (sum_c den_part) ----------
__global__ __launch_bounds__(256) void kv_reduce(const float* __restrict__ att_part,
                                                 const float* __restrict__ den_part,
                                                 float* __restrict__ att, int nchunk){
  int bh = blockIdx.x, tid = threadIdx.x;
  __shared__ float dinv[64];
  if (tid < 64){
    float d = 0.0f;
    for (int c = 0; c < nchunk; ++c) d += den_part[((size_t)(c * 256 + bh)) * 64 + tid];
    dinv[tid] = 1.0f / d;
  }
  __syncthreads();
  #pragma unroll
  for (int i = 0; i < 16; ++i){
    int e = i * 256 + tid;
    float s = 0.0f;
    for (int c = 0; c < nchunk; ++c) s += att_part[((size_t)(c * 256 + bh)) * 4096 + e];
    att[(size_t)bh * 4096 + e] = s * dinv[e >> 6];
  }
}

// ---------- y[b,t,h,l] = sum_d softmax_feat(q)[b,t,h,d] * att[b,h,d,l] ----------
__global__ __launch_bounds__(256) void q_att(const bf16* __restrict__ q, const float* __restrict__ att,
                                             bf16* __restrict__ y, int T, int ldq){
  int ntc = T >> 6;
  int idx = blockIdx.x;
  int tcb = idx % ntc; int h = (idx / ntc) & 7; int b = idx / (ntc * 8);
  __shared__ float ab[64][64];
  __shared__ bf16 qb[64][64];   // XOR-swizzled columns: c' = c ^ ((row&7)<<3)
  int tid = threadIdx.x;
  #pragma unroll
  for (int i = 0; i < 4; ++i){
    int e = i * 1024 + tid * 4;
    *(float4*)&ab[e >> 6][e & 63] = *(const float4*)&att[((size_t)(b * 8 + h)) * 4096 + e];
  }
  #pragma unroll
  for (int i = 0; i < 2; ++i){
    int rr = (tid >> 3) + i * 32;
    int cc = (tid & 7) * 8;
    s8 v = *(const s8*)&q[((size_t)(b * T + tcb * 64 + rr)) * ldq + h * 64 + cc];
    float f[8];
    #pragma unroll
    for (int j = 0; j < 8; ++j) f[j] = bf2f(((const bf16*)&v)[j]);
    float m = f[0];
    #pragma unroll
    for (int j = 1; j < 8; ++j) m = fmaxf(m, f[j]);
    m = fmaxf(m, __shfl_xor(m, 1));
    m = fmaxf(m, __shfl_xor(m, 2));
    m = fmaxf(m, __shfl_xor(m, 4));
    float s = 0.0f;
    #pragma unroll
    for (int j = 0; j < 8; ++j){ f[j] = __expf(f[j] - m); s += f[j]; }
    s += __shfl_xor(s, 1);
    s += __shfl_xor(s, 2);
    s += __shfl_xor(s, 4);
    float inv = 1.0f / s;
    s8 o;
    #pragma unroll
    for (int j = 0; j < 8; ++j) ((bf16*)&o)[j] = f2bf(f[j] * inv);
    *(s8*)&qb[rr][cc ^ ((rr & 7) << 3)] = o;
  }
  __syncthreads();
  int lg = tid & 15, tg = tid >> 4;
  int t0 = tg * 4, l0 = lg * 4;
  float acc[4][4] = {};
  for (int d8 = 0; d8 < 64; d8 += 8){
    s8 qrow[4];
    #pragma unroll
    for (int j = 0; j < 4; ++j){
      int row = t0 + j;
      qrow[j] = *(const s8*)&qb[row][d8 ^ ((row & 7) << 3)];
    }
    #pragma unroll
    for (int e = 0; e < 8; ++e){
      float4 av4 = *(const float4*)&ab[d8 + e][l0];
      float av[4] = {av4.x, av4.y, av4.z, av4.w};
      #pragma unroll
      for (int a = 0; a < 4; ++a){
        float qv = bf2f(((const bf16*)&qrow[a])[e]);
        #pragma unroll
        for (int c2 = 0; c2 < 4; ++c2) acc[a][c2] += qv * av[c2];
      }
    }
  }
  #pragma unroll
  for (int a = 0; a < 4; ++a)
    #pragma unroll
    for (int c2 = 0; c2 < 4; ++c2)
      y[((size_t)(b * T + tcb * 64 + t0 + a)) * 512 + h * 64 + l0 + c2] = f2bf(acc[a][c2]);
}

// ---------- e_all[which][b][col] = silu(emb[b]) @ W_which + b_which ; [3,32,1024] fp32 ----------
__global__ __launch_bounds__(256) void emb_gemm(const float* __restrict__ emb,
    const float* __restrict__ w0, const float* __restrict__ b0,
    const float* __restrict__ w1, const float* __restrict__ b1,
    const float* __restrict__ w2, const float* __restrict__ b2,
    float* __restrict__ e_all){
  int col = blockIdx.x * 256 + threadIdx.x;
  int b = blockIdx.y, which = blockIdx.z;
  const float* W  = (which == 0) ? w0 : (which == 1 ? w1 : w2);
  const float* bb = (which == 0) ? b0 : (which == 1 ? b1 : b2);
  __shared__ float s[512];
  for (int i = threadIdx.x; i < 512; i += 256){ float v = emb[b * 512 + i]; s[i] = silu_f(v); }
  __syncthreads();
  float acc = bb[col];
  for (int kk = 0; kk < 512; ++kk) acc += s[kk] * W[(size_t)kk * 1024 + col];
  e_all[((size_t)which * 32 + b) * 1024 + col] = acc;
}

// ---------------- bf16 MFMA GEMM, HYBRID epilogue + bf16 residual chain ----------------
// EPI: 0 = bf16 store (+bias); 2 = bf16 store gelu(+bias);
//      6 = bf16 store (+bias), times extra[row] for cols >= 1024 (fused SA QKV)
//      7 = bf16 out = f2bf(extra_f32[oi] + v)      (SA residual init)
//      8 = bf16 out = f2bf(bf16 extra[oi] + v)     (CA residual; extra==out SAFE: same-thread rd->wr)
//      9 = fp32 out = bf16 extra[oi] + v           (final residual -> d_out; swapped+float4)
// SW (swapped mfma operands -> 4 consecutive cols/lane) only for EPI 9.
// NOTE: out/out2 must never alias A (cross-block WAR race — round-10 lesson).
template<int EPI>
__global__ __launch_bounds__(256, 2) void gemm_bt(
    const bf16* __restrict__ A, const bf16* __restrict__ BT,
    const float* __restrict__ bias, void* __restrict__ out,
    const float* __restrict__ extra, void* __restrict__ out2, int M, int N, int K){
  constexpr bool SW = (EPI == 9);
  __shared__ __align__(16) bf16 As[2][128 * 32];
  __shared__ __align__(16) bf16 Bs[2][128 * 32];
  int tid = threadIdx.x;
  int w = tid >> 6, lane = tid & 63;
  int wr = w >> 1, wc = w & 1;
  // ---- XCD-aware bijective block swizzle (T1, m204 form) ----
  int nwg = gridDim.x * gridDim.y;
  int lin = blockIdx.y * gridDim.x + blockIdx.x;
  int xcd = lin & 7, sidx = lin >> 3;
  int q8 = nwg >> 3, r8 = nwg & 7;
  int wg = (xcd < r8 ? xcd * (q8 + 1) : r8 * (q8 + 1) + (xcd - r8) * q8) + sidx;
  int bn = wg % gridDim.x, bm = wg / gridDim.x;

  const bf16* Ab = A  + (size_t)bm * 128 * K;
  const bf16* Bb = BT + (size_t)bn * 128 * K;

  int srow = tid >> 2;            // tid*8 / 32
  int scol = (tid & 3) * 8;

  auto stage = [&](int buf, int k0){
    #pragma unroll
    for (int i = 0; i < 2; ++i){
      const bf16* ga = Ab + (size_t)(srow + i * 64) * K + k0 + scol;
      const bf16* gb = Bb + (size_t)(srow + i * 64) * K + k0 + scol;
      bf16* la = &As[buf][i * 2048 + w * 512];
      bf16* lb = &Bs[buf][i * 2048 + w * 512];
      __builtin_amdgcn_global_load_lds((const __attribute__((address_space(1))) void*)ga,
                                       (__attribute__((address_space(3))) void*)la, 16, 0, 0);
      __builtin_amdgcn_global_load_lds((const __attribute__((address_space(1))) void*)gb,
                                       (__attribute__((address_space(3))) void*)lb, 16, 0, 0);
    }
  };

  f4 acc[4][4];
  #pragma unroll
  for (int m = 0; m < 4; ++m)
    #pragma unroll
    for (int n = 0; n < 4; ++n)
      #pragma unroll
      for (int j = 0; j < 4; ++j) acc[m][n][j] = 0.0f;

  int nt = K >> 5;
  int arow = lane & 15;
  int koff = (lane >> 4) * 8;

  stage(0, 0);
  __syncthreads();
  int cur = 0;
  for (int t = 0; t < nt; ++t){
    if (t + 1 < nt) stage(cur ^ 1, (t + 1) * 32);
    s8 af[4], bfv[4];
    #pragma unroll
    for (int m = 0; m < 4; ++m)
      af[m] = *(const s8*)&As[cur][(wr * 64 + m * 16 + arow) * 32 + koff];
    #pragma unroll
    for (int n = 0; n < 4; ++n)
      bfv[n] = *(const s8*)&Bs[cur][(wc * 64 + n * 16 + arow) * 32 + koff];
    #pragma unroll
    for (int m = 0; m < 4; ++m)
      #pragma unroll
      for (int n = 0; n < 4; ++n){
        if constexpr (SW)
          acc[m][n] = __builtin_amdgcn_mfma_f32_16x16x32_bf16(bfv[n], af[m], acc[m][n], 0, 0, 0);
        else
          acc[m][n] = __builtin_amdgcn_mfma_f32_16x16x32_bf16(af[m], bfv[n], acc[m][n], 0, 0, 0);
      }
    __syncthreads();
    cur ^= 1;
  }

  if constexpr (SW){
    // swapped layout: row = rbase + m*16 (fixed/lane), col = cbase + n*16 + j (4 consecutive)
    int rbase = bm * 128 + wr * 64 + (lane & 15);
    int cbase = bn * 128 + wc * 64 + (lane >> 4) * 4;
    #pragma unroll
    for (int m = 0; m < 4; ++m){
      int row = rbase + m * 16;
      #pragma unroll
      for (int n = 0; n < 4; ++n){
        int col = cbase + n * 16;
        float4 bv = *(const float4*)&bias[col];
        size_t oi = (size_t)row * N + col;
        // EPI 9: fp32 out = bf16 extra + v
        h4 e4 = *(const h4*)&((const bf16*)extra)[oi];
        float4 r;
        r.x = bf2f(((const bf16*)&e4)[0]) + acc[m][n][0] + bv.x;
        r.y = bf2f(((const bf16*)&e4)[1]) + acc[m][n][1] + bv.y;
        r.z = bf2f(((const bf16*)&e4)[2]) + acc[m][n][2] + bv.z;
        r.w = bf2f(((const bf16*)&e4)[3]) + acc[m][n][3] + bv.w;
        *(float4*)&((float*)out)[oi] = r;
      }
    }
  } else {
    // original layout: row = r0 + m*16 + j, col = c0 + n*16 (lane-contiguous cols)
    int r0 = bm * 128 + wr * 64 + (lane >> 4) * 4;
    int c0 = bn * 128 + wc * 64 + (lane & 15);
    #pragma unroll
    for (int m = 0; m < 4; ++m){
      #pragma unroll
      for (int n = 0; n < 4; ++n){
        int col = c0 + n * 16;
        float bv = bias[col];
        #pragma unroll
        for (int j = 0; j < 4; ++j){
          int row = r0 + m * 16 + j;
          float v = acc[m][n][j] + bv;
          size_t oi = (size_t)row * N + col;
          if (EPI == 0){
            ((bf16*)out)[oi] = f2bf(v);
          } else if (EPI == 2){
            ((bf16*)out)[oi] = f2bf(gelu_f(v));
          } else if (EPI == 7){
            ((bf16*)out)[oi] = f2bf(extra[oi] + v);
          } else if (EPI == 8){
            ((bf16*)out)[oi] = f2bf(bf2f(((const bf16*)extra)[oi]) + v);
          } else { // EPI 6: fused QKV, mask V block (cols >= 1024)
            float sc = (col >= 1024) ? extra[row] : 1.0f;
            ((bf16*)out)[oi] = f2bf(v * sc);
          }
        }
      }
    }
  }
}

// =====================================================================================
extern "C" void kernel_launch(void* const* d_in, const int* in_sizes, int n_in,
                              void* d_out, int out_size, void* d_ws, size_t ws_size,
                              hipStream_t stream){
  const float* x    = (const float*)d_in[0];
  const float* xf   = (const float*)d_in[1];
  const float* emb  = (const float*)d_in[2];
  const float* mask = (const float*)d_in[3];
  const float* P[40];
  for (int j = 0; j < 40; ++j) P[j] = (const float*)d_in[4 + j];
  enum { SA_NG, SA_NB, SA_QW, SA_QB, SA_KW, SA_KB, SA_VW, SA_VB, SA_EW, SA_EB, SA_PG, SA_PB, SA_OW, SA_OB,
         CA_NG, CA_NB, CA_TG, CA_TB, CA_QW, CA_QB, CA_KW, CA_KB, CA_VW, CA_VB, CA_EW, CA_EB, CA_PG, CA_PB, CA_OW, CA_OB,
         F_W1, F_B1, F_W2, F_B2, F_EW, F_EB, F_PG, F_PB, F_OW, F_OB };

  char* wp = (char*)d_ws;
  auto alloc = [&](size_t bytes){ void* p = (void*)wp; wp += (bytes + 255) & ~(size_t)255; return p; };

  const size_t SQ = (size_t)512 * 512 * 2;       // 512x512 bf16
  bf16* WT_saqkv = (bf16*)alloc(3 * SQ);          // [1536,512]
  bf16* WT_saout = (bf16*)alloc(SQ);
  bf16* WT_caq   = (bf16*)alloc(SQ);
  bf16* WT_cakv  = (bf16*)alloc(2 * SQ);          // [1024,512]
  bf16* WT_caout = (bf16*)alloc(SQ);
  bf16* WT_f1    = (bf16*)alloc((size_t)2048 * 512 * 2);
  bf16* WT_f2    = (bf16*)alloc((size_t)512 * 2048 * 2);
  bf16* WT_fout  = (bf16*)alloc(SQ);
  float* cat_sab = (float*)alloc(1536 * 4);
  float* cat_cab = (float*)alloc(1024 * 4);
  float* e_all   = (float*)alloc((size_t)3 * 32 * 1024 * 4);

  const size_t BTD2 = (size_t)32768 * 512 * 2;    // 32 MB (bf16 [B*T, D])
  bf16* bxn  = (bf16*)alloc(BTD2);                // also: r1/r2 residual (bf16)
  bf16* bqkv = (bf16*)alloc(3 * BTD2);            // QKV; FFN hidden = bqkv..by span (128MB)
  bf16* by   = (bf16*)alloc(BTD2);
  bf16* bs   = (bf16*)alloc(BTD2);
  bf16* btn  = (bf16*)alloc((size_t)8192 * 512 * 2);
  float* att_part = (float*)alloc((size_t)4 * 256 * 4096 * 4);   // up to 4 chunks
  float* den_part = (float*)alloc((size_t)4 * 256 * 64 * 4);
  float* batt = (float*)alloc((size_t)256 * 4096 * 4);
  bf16* bh1 = bqkv;                               // FFN hidden [32768,2048] overlays bqkv+by (contiguous 128MB)
  bf16* bq_ca  = bqkv;                            // CA q  [32768,512]
  bf16* bkv_ca = bqkv + BTD2 / 2;                 // CA kv [8192,1024]

  // ---- single batched transpose dispatch (11 matrices) ----
  TPack tp;
  auto set = [&](int i, const float* s, bf16* d, int K, int N){
    tp.d[i].src = s; tp.d[i].dst = d; tp.d[i].K = K; tp.d[i].N = N;
    tp.d[i].tiles = (K >> 5) * (N >> 5);
  };
  set(0,  P[SA_QW], WT_saqkv,              512, 512);
  set(1,  P[SA_KW], WT_saqkv + 512 * 512,  512, 512);
  set(2,  P[SA_VW], WT_saqkv + 1024 * 512, 512, 512);
  set(3,  P[SA_OW], WT_saout,              512, 512);
  set(4,  P[CA_QW], WT_caq,                512, 512);
  set(5,  P[CA_KW], WT_cakv,               512, 512);
  set(6,  P[CA_VW], WT_cakv + 512 * 512,   512, 512);
  set(7,  P[CA_OW], WT_caout,              512, 512);
  set(8,  P[F_OW],  WT_fout,               512, 512);
  set(9,  P[F_W1],  WT_f1,                 512, 2048);
  set(10, P[F_W2],  WT_f2,                 2048, 512);
  int total_tiles = 9 * 256 + 1024 + 1024;   // 4352
  transpose_all<<<total_tiles, dim3(32, 8), 0, stream>>>(tp);

  concat_bias<<<6, 256, 0, stream>>>(P[SA_QB], P[SA_KB], P[SA_VB], P[CA_KB], P[CA_VB], cat_sab, cat_cab);

  emb_gemm<<<dim3(4, 32, 3), 256, 0, stream>>>(emb, P[SA_EW], P[SA_EB], P[CA_EW], P[CA_EB],
                                               P[F_EW], P[F_EB], e_all);

  dim3 g512(4, 256);   // N=512, M=32768

  // ---------------- self-attention ----------------
  ln_kernel<<<8192, 256, 0, stream>>>(x, bxn, P[SA_NG], P[SA_NB]);
  gemm_bt<6><<<dim3(12, 256), 256, 0, stream>>>(bxn, WT_saqkv, cat_sab, bqkv, mask, nullptr, 32768, 1536, 512);
  kv_outer<<<dim3(256, 4), 256, 0, stream>>>(bqkv + 512, bqkv + 1024, mask, att_part, den_part, 1024, 1536, 256);
  kv_reduce<<<256, 256, 0, stream>>>(att_part, den_part, batt, 4);
  q_att<<<4096, 256, 0, stream>>>(bqkv, batt, by, 1024, 1536);
  styl_ln_kernel<<<8192, 256, 0, stream>>>(by, e_all, P[SA_PG], P[SA_PB], bs, 1024);
  // r1(=bxn) = x + sa_out   (bf16 residual; A=bs, out=bxn — no alias; bxn dead since QKV gemm)
  gemm_bt<7><<<g512, 256, 0, stream>>>(bs, WT_saout, P[SA_OB], bxn, x, nullptr, 32768, 512, 512);

  // ---------------- cross-attention ----------------
  ln_bf16_kernel<<<8192, 256, 0, stream>>>(bxn, by, P[CA_NG], P[CA_NB]);   // by = LN(r1)
  ln_kernel<<<2048, 256, 0, stream>>>(xf, btn, P[CA_TG], P[CA_TB]);
  gemm_bt<0><<<g512, 256, 0, stream>>>(by, WT_caq, P[CA_QB], bq_ca, nullptr, nullptr, 32768, 512, 512);
  gemm_bt<0><<<dim3(8, 64), 256, 0, stream>>>(btn, WT_cakv, cat_cab, bkv_ca, nullptr, nullptr, 8192, 1024, 512);
  kv_outer<<<dim3(256, 2), 256, 0, stream>>>(bkv_ca, bkv_ca + 512, nullptr, att_part, den_part, 256, 1024, 128);
  kv_reduce<<<256, 256, 0, stream>>>(att_part, den_part, batt, 2);
  q_att<<<4096, 256, 0, stream>>>(bq_ca, batt, by, 1024, 512);
  styl_ln_kernel<<<8192, 256, 0, stream>>>(by, e_all + 32 * 1024, P[CA_PG], P[CA_PB], bs, 1024);
  // r2(=bxn) = r1 + ca_out  (A=bs; extra==out=bxn: same-thread element rd->wr, safe & deterministic)
  gemm_bt<8><<<g512, 256, 0, stream>>>(bs, WT_caout, P[CA_OB], bxn, (const float*)bxn, nullptr, 32768, 512, 512);

  // ---------------- FFN ----------------
  // FFN input is the RESIDUAL r2 (=bxn), not the styl output (round-17 bug).
  gemm_bt<2><<<dim3(16, 256), 256, 0, stream>>>(bxn, WT_f1, P[F_B1], bh1, nullptr, nullptr, 32768, 2048, 512);
  gemm_bt<0><<<dim3(4, 256), 256, 0, stream>>>(bh1, WT_f2, P[F_B2], bs, nullptr, nullptr, 32768, 512, 2048);
  styl_ln_kernel<<<8192, 256, 0, stream>>>(bs, e_all + 2 * 32 * 1024, P[F_PG], P[F_PB], by, 1024);
  // d_out = r2 + ffn_out   (single fp32 write; A=by, extra=bxn, out=d_out — no alias)
  gemm_bt<9><<<g512, 256, 0, stream>>>(by, WT_fout, P[F_OB], d_out, (const float*)bxn, nullptr, 32768, 512, 512);
}